// Round 1
// baseline (1296.068 us; speedup 1.0000x reference)
//
#include <hip/hip_runtime.h>

typedef __bf16 bf16x8 __attribute__((ext_vector_type(8)));
typedef float f32x4 __attribute__((ext_vector_type(4)));

#define MFMA_BF16(a,b,c) __builtin_amdgcn_mfma_f32_16x16x32_bf16(a,b,c,0,0,0)

__device__ __forceinline__ unsigned short f2bf(float f) {
  unsigned int u = __float_as_uint(f);
  u = (u + 0x7FFFu + ((u >> 16) & 1u)) >> 16;
  return (unsigned short)u;
}

__device__ __forceinline__ void gload16(void* g, void* l) {
  __builtin_amdgcn_global_load_lds(
      (__attribute__((address_space(1))) void*)g,
      (__attribute__((address_space(3))) void*)l, 16, 0, 0);
}

// ---------------- convert x (fp32) -> bf16 ----------------
__global__ __launch_bounds__(256) void k_convx(const float* __restrict__ x,
                                               unsigned short* __restrict__ xb) {
  int i = (blockIdx.x * 256 + threadIdx.x) * 4;
  float4 v = *reinterpret_cast<const float4*>(x + i);
  ushort4 o;
  o.x = f2bf(v.x); o.y = f2bf(v.y); o.z = f2bf(v.z); o.w = f2bf(v.w);
  *reinterpret_cast<ushort4*>(xb + i) = o;
}

// ---------------- transpose-convert W (fp32 [1024][1024]) -> WT bf16 [N][K] ----------------
__global__ __launch_bounds__(256) void k_transw(const float* __restrict__ W,
                                                unsigned short* __restrict__ WT) {
  __shared__ float t[32][33];
  int bx = blockIdx.x * 32;  // n tile
  int by = blockIdx.y * 32;  // k tile
  int tx = threadIdx.x & 31;
  int ty = threadIdx.x >> 5;  // 0..7
#pragma unroll
  for (int i = 0; i < 32; i += 8)
    t[ty + i][tx] = W[(size_t)(by + ty + i) * 1024 + bx + tx];
  __syncthreads();
#pragma unroll
  for (int i = 0; i < 32; i += 8)
    WT[(size_t)(bx + ty + i) * 1024 + by + tx] = f2bf(t[tx][ty + i]);
}

// ---------------- GEMM: C[M,N] = A[M,K] (bf16) @ BT[N,K]^T (bf16) ----------------
// EPI 0: fused QKV epilogue (N=3072: [0,1024)=Q, [1024,2048)=K, [2048,3072)=V)
// EPI 1: plain fp32 store
template <int EPI>
__global__ __launch_bounds__(256) void k_gemm(
    const unsigned short* __restrict__ A, const unsigned short* __restrict__ BT, int K,
    unsigned short* __restrict__ Qh, unsigned short* __restrict__ Kh,
    unsigned short* __restrict__ VhT, const float* __restrict__ alphaPtr,
    float* __restrict__ Out) {
  __shared__ __align__(16) unsigned short As[128][32];
  __shared__ __align__(16) unsigned short Bs[128][32];
  const int tid = threadIdx.x;
  const int wave = tid >> 6, lane = tid & 63;
  const int l15 = lane & 15, lg = lane >> 4;
  const int wr = wave >> 1, wc = wave & 1;
  const int bm = blockIdx.x, bn = blockIdx.y;

  f32x4 acc[4][4] = {};
  const unsigned short* Ab = A + (size_t)bm * 128 * K;
  const unsigned short* Bb = BT + (size_t)bn * 128 * K;

  const int r0 = tid >> 2, q0 = (tid & 3) * 8;           // chunk 0: rows 0..63
  const int r1 = (tid + 256) >> 2, q1 = q0;              // chunk 1: rows 64..127
  char* ldsA = (char*)&As[0][0] + wave * 1024;
  char* ldsB = (char*)&Bs[0][0] + wave * 1024;

  for (int k0 = 0; k0 < K; k0 += 32) {
    gload16((void*)(Ab + (size_t)r0 * K + k0 + q0), ldsA);
    gload16((void*)(Ab + (size_t)r1 * K + k0 + q1), ldsA + 4096);
    gload16((void*)(Bb + (size_t)r0 * K + k0 + q0), ldsB);
    gload16((void*)(Bb + (size_t)r1 * K + k0 + q1), ldsB + 4096);
    __syncthreads();
    bf16x8 af[4], bfr[4];
#pragma unroll
    for (int mi = 0; mi < 4; ++mi)
      af[mi] = *reinterpret_cast<const bf16x8*>(&As[wr * 64 + mi * 16 + l15][lg * 8]);
#pragma unroll
    for (int ni = 0; ni < 4; ++ni)
      bfr[ni] = *reinterpret_cast<const bf16x8*>(&Bs[wc * 64 + ni * 16 + l15][lg * 8]);
#pragma unroll
    for (int mi = 0; mi < 4; ++mi)
#pragma unroll
      for (int ni = 0; ni < 4; ++ni)
        acc[mi][ni] = MFMA_BF16(af[mi], bfr[ni], acc[mi][ni]);
    __syncthreads();
  }

  if (EPI == 0) {
    float av = alphaPtr[0];
#pragma unroll
    for (int ni = 0; ni < 4; ++ni) {
      int n = bn * 128 + wc * 64 + ni * 16 + l15;
      int t = n >> 10, nc = n & 1023;
      int hh = nc >> 6, dd = nc & 63;
#pragma unroll
      for (int mi = 0; mi < 4; ++mi) {
        int row = bm * 128 + wr * 64 + mi * 16 + lg * 4;
#pragma unroll
        for (int r = 0; r < 4; ++r) {
          int rr = row + r;
          int b = rr >> 11, s = rr & 2047;
          size_t bhi = (size_t)b * 16 + hh;
          float v = acc[mi][ni][r];
          if (t == 0) {
            v += 0.1f * sinf(v);
            Qh[(bhi * 2048 + s) * 64 + dd] = f2bf(v);
          } else if (t == 1) {
            v += 0.1f * cosf(v);
            Kh[(bhi * 2048 + s) * 64 + dd] = f2bf(v);
          } else {
            v += av * 0.1f * tanhf(v);
            VhT[(bhi * 64 + dd) * 2048 + s] = f2bf(v);
          }
        }
      }
    }
  } else {
#pragma unroll
    for (int ni = 0; ni < 4; ++ni) {
      int n = bn * 128 + wc * 64 + ni * 16 + l15;
#pragma unroll
      for (int mi = 0; mi < 4; ++mi) {
        int row = bm * 128 + wr * 64 + mi * 16 + lg * 4;
#pragma unroll
        for (int r = 0; r < 4; ++r)
          Out[(size_t)(row + r) * 1024 + n] = acc[mi][ni][r];
      }
    }
  }
}

// ---------------- flash attention ----------------
// grid: (S/128, B*H). 4 waves, each owns 32 q rows. KB=64 key tiles.
__global__ __launch_bounds__(256) void k_attn(const unsigned short* __restrict__ Qh,
                                              const unsigned short* __restrict__ Kh,
                                              const unsigned short* __restrict__ VhT,
                                              unsigned short* __restrict__ AO) {
  __shared__ __align__(16) unsigned short Ks[64][72];   // padded: 36-dword stride
  __shared__ __align__(16) unsigned short VTs[64][72];
  __shared__ __align__(16) unsigned short Ps[4][32][72];
  const int tid = threadIdx.x;
  const int wave = tid >> 6, lane = tid & 63;
  const int l15 = lane & 15, lg = lane >> 4;
  const int qb = blockIdx.x, bh = blockIdx.y;
  const int b = bh >> 4, h = bh & 15;
  const int wq0 = wave * 32;

  const unsigned short* Qb = Qh + ((size_t)bh * 2048 + qb * 128) * 64;
  const unsigned short* Kb = Kh + (size_t)bh * 2048 * 64;
  const unsigned short* Vb = VhT + (size_t)bh * 64 * 2048;

  bf16x8 qf[2][2];
#pragma unroll
  for (int i = 0; i < 2; ++i)
#pragma unroll
    for (int ks = 0; ks < 2; ++ks)
      qf[i][ks] = *reinterpret_cast<const bf16x8*>(
          Qb + (size_t)(wq0 + i * 16 + l15) * 64 + ks * 32 + lg * 8);

  float mrun[2][4], lrun[2][4];
  f32x4 o[2][4] = {};
#pragma unroll
  for (int i = 0; i < 2; ++i)
#pragma unroll
    for (int r = 0; r < 4; ++r) { mrun[i][r] = -3.0e38f; lrun[i][r] = 0.f; }

  for (int k0 = 0; k0 < 2048; k0 += 64) {
#pragma unroll
    for (int j = 0; j < 2; ++j) {
      int c = tid + j * 256;
      int r = c >> 3, cc = (c & 7) * 8;
      *reinterpret_cast<uint4*>(&Ks[r][cc]) =
          *reinterpret_cast<const uint4*>(Kb + (size_t)(k0 + r) * 64 + cc);
      *reinterpret_cast<uint4*>(&VTs[r][cc]) =
          *reinterpret_cast<const uint4*>(Vb + (size_t)r * 2048 + k0 + cc);
    }
    __syncthreads();

    f32x4 s[2][4] = {};
#pragma unroll
    for (int kf = 0; kf < 4; ++kf)
#pragma unroll
      for (int ks = 0; ks < 2; ++ks) {
        bf16x8 kb = *reinterpret_cast<const bf16x8*>(&Ks[kf * 16 + l15][ks * 32 + lg * 8]);
#pragma unroll
        for (int i = 0; i < 2; ++i) s[i][kf] = MFMA_BF16(qf[i][ks], kb, s[i][kf]);
      }

#pragma unroll
    for (int i = 0; i < 2; ++i) {
#pragma unroll
      for (int kf = 0; kf < 4; ++kf) s[i][kf] *= 0.125f;
#pragma unroll
      for (int r = 0; r < 4; ++r) {
        float v = fmaxf(fmaxf(s[i][0][r], s[i][1][r]), fmaxf(s[i][2][r], s[i][3][r]));
        v = fmaxf(v, __shfl_xor(v, 1));
        v = fmaxf(v, __shfl_xor(v, 2));
        v = fmaxf(v, __shfl_xor(v, 4));
        v = fmaxf(v, __shfl_xor(v, 8));
        float mn = fmaxf(mrun[i][r], v);
        float corr = __expf(mrun[i][r] - mn);
        mrun[i][r] = mn;
        float sum = 0.f;
#pragma unroll
        for (int kf = 0; kf < 4; ++kf) {
          float p0 = __expf(s[i][kf][r] - mn);
          s[i][kf][r] = p0;
          sum += p0;
        }
        sum += __shfl_xor(sum, 1);
        sum += __shfl_xor(sum, 2);
        sum += __shfl_xor(sum, 4);
        sum += __shfl_xor(sum, 8);
        lrun[i][r] = lrun[i][r] * corr + sum;
#pragma unroll
        for (int df = 0; df < 4; ++df) o[i][df][r] *= corr;
      }
    }

    // P -> LDS (bf16), per-wave buffer
#pragma unroll
    for (int i = 0; i < 2; ++i)
#pragma unroll
      for (int kf = 0; kf < 4; ++kf)
#pragma unroll
        for (int r = 0; r < 4; ++r)
          Ps[wave][i * 16 + lg * 4 + r][kf * 16 + l15] = f2bf(s[i][kf][r]);
    asm volatile("" ::: "memory");

    // PV
#pragma unroll
    for (int ks2 = 0; ks2 < 2; ++ks2) {
      bf16x8 pa[2];
#pragma unroll
      for (int i = 0; i < 2; ++i)
        pa[i] = *reinterpret_cast<const bf16x8*>(&Ps[wave][i * 16 + l15][ks2 * 32 + lg * 8]);
#pragma unroll
      for (int df = 0; df < 4; ++df) {
        bf16x8 vb = *reinterpret_cast<const bf16x8*>(&VTs[df * 16 + l15][ks2 * 32 + lg * 8]);
#pragma unroll
        for (int i = 0; i < 2; ++i) o[i][df] = MFMA_BF16(pa[i], vb, o[i][df]);
      }
    }
    __syncthreads();
  }

#pragma unroll
  for (int i = 0; i < 2; ++i)
#pragma unroll
    for (int df = 0; df < 4; ++df)
#pragma unroll
      for (int r = 0; r < 4; ++r) {
        float v = o[i][df][r] / lrun[i][r];
        int q = qb * 128 + wq0 + i * 16 + lg * 4 + r;
        int d = df * 16 + l15;
        AO[((size_t)b * 2048 + q) * 1024 + h * 64 + d] = f2bf(v);
      }
}

extern "C" void kernel_launch(void* const* d_in, const int* in_sizes, int n_in,
                              void* d_out, int out_size, void* d_ws, size_t ws_size,
                              hipStream_t stream) {
  const float* x = (const float*)d_in[0];
  const float* Wq = (const float*)d_in[1];
  const float* Wk = (const float*)d_in[2];
  const float* Wv = (const float*)d_in[3];
  const float* Wo = (const float*)d_in[4];
  const float* alpha = (const float*)d_in[5];
  float* out = (float*)d_out;

  char* ws = (char*)d_ws;
  unsigned short* xb  = (unsigned short*)(ws);                 // 16 MiB
  unsigned short* WT3 = (unsigned short*)(ws + 16777216);      // 6 MiB (Wq^T|Wk^T|Wv^T)
  unsigned short* WoT = (unsigned short*)(ws + 23068672);      // 2 MiB
  unsigned short* Qh  = (unsigned short*)(ws + 25165824);      // 16 MiB [B,H,S,64]
  unsigned short* Kh  = (unsigned short*)(ws + 41943040);      // 16 MiB [B,H,S,64]
  unsigned short* VhT = (unsigned short*)(ws + 58720256);      // 16 MiB [B,H,64,S]
  unsigned short* AO  = (unsigned short*)(ws + 75497472);      // 16 MiB [B,S,1024]

  k_convx<<<dim3(8192), dim3(256), 0, stream>>>(x, xb);
  k_transw<<<dim3(32, 32), dim3(256), 0, stream>>>(Wq, WT3);
  k_transw<<<dim3(32, 32), dim3(256), 0, stream>>>(Wk, WT3 + 1024 * 1024);
  k_transw<<<dim3(32, 32), dim3(256), 0, stream>>>(Wv, WT3 + 2 * 1024 * 1024);
  k_transw<<<dim3(32, 32), dim3(256), 0, stream>>>(Wo, WoT);

  k_gemm<0><<<dim3(64, 24), dim3(256), 0, stream>>>(xb, WT3, 1024, Qh, Kh, VhT, alpha, nullptr);
  k_attn<<<dim3(16, 64), dim3(256), 0, stream>>>(Qh, Kh, VhT, AO);
  k_gemm<1><<<dim3(64, 8), dim3(256), 0, stream>>>(AO, WoT, 1024, nullptr, nullptr, nullptr, nullptr, out);
}

// Round 2
// 483.414 us; speedup vs baseline: 2.6811x; 2.6811x over previous
//
#include <hip/hip_runtime.h>

typedef __bf16 bf16x8 __attribute__((ext_vector_type(8)));
typedef float f32x4 __attribute__((ext_vector_type(4)));
typedef unsigned short ushort8 __attribute__((ext_vector_type(8)));

#define MFMA_BF16(a,b,c) __builtin_amdgcn_mfma_f32_16x16x32_bf16(a,b,c,0,0,0)

__device__ __forceinline__ unsigned short f2bf(float f) {
  unsigned int u = __float_as_uint(f);
  u = (u + 0x7FFFu + ((u >> 16) & 1u)) >> 16;
  return (unsigned short)u;
}

__device__ __forceinline__ void gload16(const void* g, void* l) {
  __builtin_amdgcn_global_load_lds(
      (const __attribute__((address_space(1))) void*)g,
      (__attribute__((address_space(3))) void*)l, 16, 0, 0);
}

// ---------------- convert x (fp32) -> bf16 ----------------
__global__ __launch_bounds__(256) void k_convx(const float* __restrict__ x,
                                               unsigned short* __restrict__ xb) {
  int i = (blockIdx.x * 256 + threadIdx.x) * 4;
  float4 v = *reinterpret_cast<const float4*>(x + i);
  ushort4 o;
  o.x = f2bf(v.x); o.y = f2bf(v.y); o.z = f2bf(v.z); o.w = f2bf(v.w);
  *reinterpret_cast<ushort4*>(xb + i) = o;
}

// ---------------- transpose-convert W (fp32 [1024][1024]) -> WT bf16 [N][K] ----------------
__global__ __launch_bounds__(256) void k_transw(const float* __restrict__ W,
                                                unsigned short* __restrict__ WT) {
  __shared__ float t[32][33];
  int bx = blockIdx.x * 32;  // n tile
  int by = blockIdx.y * 32;  // k tile
  int tx = threadIdx.x & 31;
  int ty = threadIdx.x >> 5;  // 0..7
#pragma unroll
  for (int i = 0; i < 32; i += 8)
    t[ty + i][tx] = W[(size_t)(by + ty + i) * 1024 + bx + tx];
  __syncthreads();
#pragma unroll
  for (int i = 0; i < 32; i += 8)
    WT[(size_t)(bx + ty + i) * 1024 + by + tx] = f2bf(t[tx][ty + i]);
}

// ---------------- GEMM: C[M,N] = A[M,K] (bf16) @ BT[N,K]^T (bf16) ----------------
// EPI 0: fused QKV epilogue. N=3072 logical; region t=bn>>3 (Q/K/V), each written
//        as a [8192][1024] bf16 matrix with the elementwise transform applied.
//        All stores staged through LDS -> 256B contiguous aligned runs.
// EPI 1: plain fp32 store [8192][1024]
template <int EPI>
__global__ __launch_bounds__(256) void k_gemm(
    const unsigned short* __restrict__ A, const unsigned short* __restrict__ BT, int K,
    unsigned short* __restrict__ Qf, unsigned short* __restrict__ Kf,
    unsigned short* __restrict__ Vf, const float* __restrict__ alphaPtr,
    float* __restrict__ Out) {
  // union: loop uses As(8KB)+Bs(8KB) at smem[0..8191]; epilogue uses Ls[128][136]
  __shared__ __align__(16) unsigned short smem[128 * 136];
  unsigned short* AsBase = smem;                      // [128][32]
  unsigned short* BsBase = smem + 128 * 32;           // [128][32]
  const int tid = threadIdx.x;
  const int wave = tid >> 6, lane = tid & 63;
  const int l15 = lane & 15, lg = lane >> 4;
  const int wr = wave >> 1, wc = wave & 1;
  const int bm = blockIdx.x, bn = blockIdx.y;

  f32x4 acc[4][4] = {};
  const unsigned short* Ab = A + (size_t)bm * 128 * K;
  const unsigned short* Bb = BT + (size_t)bn * 128 * K;

  const int r0 = tid >> 2, q0 = (tid & 3) * 8;  // chunk 0: rows 0..63
  const int r1 = r0 + 64;                        // chunk 1: rows 64..127
  char* ldsA = (char*)AsBase + wave * 1024;
  char* ldsB = (char*)BsBase + wave * 1024;

  for (int k0 = 0; k0 < K; k0 += 32) {
    gload16((const void*)(Ab + (size_t)r0 * K + k0 + q0), ldsA);
    gload16((const void*)(Ab + (size_t)r1 * K + k0 + q0), ldsA + 4096);
    gload16((const void*)(Bb + (size_t)r0 * K + k0 + q0), ldsB);
    gload16((const void*)(Bb + (size_t)r1 * K + k0 + q0), ldsB + 4096);
    __syncthreads();
    bf16x8 af[4], bfr[4];
#pragma unroll
    for (int mi = 0; mi < 4; ++mi)
      af[mi] = *reinterpret_cast<const bf16x8*>(&AsBase[(wr * 64 + mi * 16 + l15) * 32 + lg * 8]);
#pragma unroll
    for (int ni = 0; ni < 4; ++ni)
      bfr[ni] = *reinterpret_cast<const bf16x8*>(&BsBase[(wc * 64 + ni * 16 + l15) * 32 + lg * 8]);
#pragma unroll
    for (int mi = 0; mi < 4; ++mi)
#pragma unroll
      for (int ni = 0; ni < 4; ++ni)
        acc[mi][ni] = MFMA_BF16(af[mi], bfr[ni], acc[mi][ni]);
    __syncthreads();
  }

  if (EPI == 0) {
    const float av = alphaPtr[0];
    const int t = bn >> 3;  // 0=Q 1=K 2=V (whole block in one region)
    // fp32 transform -> bf16 -> LDS tile Ls[128 rows][128 cols] (stride 136)
#pragma unroll
    for (int mi = 0; mi < 4; ++mi)
#pragma unroll
      for (int ni = 0; ni < 4; ++ni)
#pragma unroll
        for (int r = 0; r < 4; ++r) {
          int row = wr * 64 + mi * 16 + lg * 4 + r;
          int col = wc * 64 + ni * 16 + l15;
          float v = acc[mi][ni][r];
          if (t == 0) v += 0.1f * sinf(v);
          else if (t == 1) v += 0.1f * cosf(v);
          else v += av * 0.1f * tanhf(v);
          smem[row * 136 + col] = f2bf(v);
        }
    __syncthreads();
    unsigned short* dst = (t == 0) ? Qf : (t == 1) ? Kf : Vf;
    const int c16 = tid & 15, rb = tid >> 4;
    const int ncol0 = (bn & 7) * 128;
#pragma unroll
    for (int i2 = 0; i2 < 8; ++i2) {
      int srow = rb + i2 * 16;
      uint4 val = *reinterpret_cast<const uint4*>(&smem[srow * 136 + c16 * 8]);
      *reinterpret_cast<uint4*>(dst + (size_t)(bm * 128 + srow) * 1024 + ncol0 + c16 * 8) = val;
    }
  } else {
#pragma unroll
    for (int ni = 0; ni < 4; ++ni) {
      int n = bn * 128 + wc * 64 + ni * 16 + l15;
#pragma unroll
      for (int mi = 0; mi < 4; ++mi) {
        int row = bm * 128 + wr * 64 + mi * 16 + lg * 4;
#pragma unroll
        for (int r = 0; r < 4; ++r)
          Out[(size_t)(row + r) * 1024 + n] = acc[mi][ni][r];
      }
    }
  }
}

// ---------------- flash attention ----------------
// Q,K,V all [4][2048][1024] bf16 (heads interleaved: col = h*64+d).
// grid: (S/128, B*H). 4 waves, each owns 32 q rows. KB=64 key tiles.
__global__ __launch_bounds__(256) void k_attn(const unsigned short* __restrict__ Qf,
                                              const unsigned short* __restrict__ Kf,
                                              const unsigned short* __restrict__ Vf,
                                              unsigned short* __restrict__ AO) {
  __shared__ __align__(16) unsigned short Ks[64][72];   // [key][d], padded
  __shared__ __align__(16) unsigned short VTs[64][72];  // [d][key], padded
  __shared__ __align__(16) unsigned short Ps[4][32][72];
  const int tid = threadIdx.x;
  const int wave = tid >> 6, lane = tid & 63;
  const int l15 = lane & 15, lg = lane >> 4;
  const int qb = blockIdx.x, bh = blockIdx.y;
  const int b = bh >> 4, h = bh & 15;
  const int wq0 = wave * 32;

  const unsigned short* Qb = Qf + (size_t)b * 2048 * 1024 + (size_t)qb * 128 * 1024 + h * 64;
  const unsigned short* Kb = Kf + (size_t)b * 2048 * 1024 + h * 64;
  const unsigned short* Vb = Vf + (size_t)b * 2048 * 1024 + h * 64;

  bf16x8 qf[2][2];
#pragma unroll
  for (int i = 0; i < 2; ++i)
#pragma unroll
    for (int ks = 0; ks < 2; ++ks)
      qf[i][ks] = *reinterpret_cast<const bf16x8*>(
          Qb + (size_t)(wq0 + i * 16 + l15) * 1024 + ks * 32 + lg * 8);

  float mrun[2][4], lrun[2][4];
  f32x4 o[2][4] = {};
#pragma unroll
  for (int i = 0; i < 2; ++i)
#pragma unroll
    for (int r = 0; r < 4; ++r) { mrun[i][r] = -3.0e38f; lrun[i][r] = 0.f; }

  for (int k0 = 0; k0 < 2048; k0 += 64) {
#pragma unroll
    for (int j = 0; j < 2; ++j) {
      int c = tid + j * 256;
      int r = c >> 3, cc = (c & 7) * 8;
      *reinterpret_cast<uint4*>(&Ks[r][cc]) =
          *reinterpret_cast<const uint4*>(Kb + (size_t)(k0 + r) * 1024 + cc);
      ushort8 vv = *reinterpret_cast<const ushort8*>(Vb + (size_t)(k0 + r) * 1024 + cc);
#pragma unroll
      for (int e = 0; e < 8; ++e) VTs[cc + e][r] = vv[e];  // transpose into [d][key]
    }
    __syncthreads();

    f32x4 s[2][4] = {};
#pragma unroll
    for (int kf = 0; kf < 4; ++kf)
#pragma unroll
      for (int ks = 0; ks < 2; ++ks) {
        bf16x8 kb = *reinterpret_cast<const bf16x8*>(&Ks[kf * 16 + l15][ks * 32 + lg * 8]);
#pragma unroll
        for (int i = 0; i < 2; ++i) s[i][kf] = MFMA_BF16(qf[i][ks], kb, s[i][kf]);
      }

#pragma unroll
    for (int i = 0; i < 2; ++i) {
#pragma unroll
      for (int kf = 0; kf < 4; ++kf) s[i][kf] *= 0.125f;
#pragma unroll
      for (int r = 0; r < 4; ++r) {
        float v = fmaxf(fmaxf(s[i][0][r], s[i][1][r]), fmaxf(s[i][2][r], s[i][3][r]));
        v = fmaxf(v, __shfl_xor(v, 1));
        v = fmaxf(v, __shfl_xor(v, 2));
        v = fmaxf(v, __shfl_xor(v, 4));
        v = fmaxf(v, __shfl_xor(v, 8));
        float mn = fmaxf(mrun[i][r], v);
        float corr = __expf(mrun[i][r] - mn);
        mrun[i][r] = mn;
        float sum = 0.f;
#pragma unroll
        for (int kf = 0; kf < 4; ++kf) {
          float p0 = __expf(s[i][kf][r] - mn);
          s[i][kf][r] = p0;
          sum += p0;
        }
        sum += __shfl_xor(sum, 1);
        sum += __shfl_xor(sum, 2);
        sum += __shfl_xor(sum, 4);
        sum += __shfl_xor(sum, 8);
        lrun[i][r] = lrun[i][r] * corr + sum;
#pragma unroll
        for (int df = 0; df < 4; ++df) o[i][df][r] *= corr;
      }
    }

    // P -> LDS (bf16), per-wave buffer
#pragma unroll
    for (int i = 0; i < 2; ++i)
#pragma unroll
      for (int kf = 0; kf < 4; ++kf)
#pragma unroll
        for (int r = 0; r < 4; ++r)
          Ps[wave][i * 16 + lg * 4 + r][kf * 16 + l15] = f2bf(s[i][kf][r]);
    asm volatile("" ::: "memory");

    // PV
#pragma unroll
    for (int ks2 = 0; ks2 < 2; ++ks2) {
      bf16x8 pa[2];
#pragma unroll
      for (int i = 0; i < 2; ++i)
        pa[i] = *reinterpret_cast<const bf16x8*>(&Ps[wave][i * 16 + l15][ks2 * 32 + lg * 8]);
#pragma unroll
      for (int df = 0; df < 4; ++df) {
        bf16x8 vb = *reinterpret_cast<const bf16x8*>(&VTs[df * 16 + l15][ks2 * 32 + lg * 8]);
#pragma unroll
        for (int i = 0; i < 2; ++i) o[i][df] = MFMA_BF16(pa[i], vb, o[i][df]);
      }
    }
    __syncthreads();
  }

#pragma unroll
  for (int i = 0; i < 2; ++i)
#pragma unroll
    for (int df = 0; df < 4; ++df)
#pragma unroll
      for (int r = 0; r < 4; ++r) {
        float v = o[i][df][r] / lrun[i][r];
        int q = qb * 128 + wq0 + i * 16 + lg * 4 + r;
        int d = df * 16 + l15;
        AO[((size_t)b * 2048 + q) * 1024 + h * 64 + d] = f2bf(v);
      }
}

extern "C" void kernel_launch(void* const* d_in, const int* in_sizes, int n_in,
                              void* d_out, int out_size, void* d_ws, size_t ws_size,
                              hipStream_t stream) {
  const float* x = (const float*)d_in[0];
  const float* Wq = (const float*)d_in[1];
  const float* Wk = (const float*)d_in[2];
  const float* Wv = (const float*)d_in[3];
  const float* Wo = (const float*)d_in[4];
  const float* alpha = (const float*)d_in[5];
  float* out = (float*)d_out;

  char* ws = (char*)d_ws;
  unsigned short* xb  = (unsigned short*)(ws);                 // 16 MiB
  unsigned short* WT3 = (unsigned short*)(ws + 16777216);      // 6 MiB (Wq^T|Wk^T|Wv^T)
  unsigned short* WoT = (unsigned short*)(ws + 23068672);      // 2 MiB
  unsigned short* Qf  = (unsigned short*)(ws + 25165824);      // 16 MiB [8192][1024]
  unsigned short* Kf  = (unsigned short*)(ws + 41943040);      // 16 MiB [8192][1024]
  unsigned short* Vf  = (unsigned short*)(ws + 58720256);      // 16 MiB [8192][1024]
  unsigned short* AO  = (unsigned short*)(ws + 75497472);      // 16 MiB [8192][1024]

  k_convx<<<dim3(8192), dim3(256), 0, stream>>>(x, xb);
  k_transw<<<dim3(32, 32), dim3(256), 0, stream>>>(Wq, WT3);
  k_transw<<<dim3(32, 32), dim3(256), 0, stream>>>(Wk, WT3 + 1024 * 1024);
  k_transw<<<dim3(32, 32), dim3(256), 0, stream>>>(Wv, WT3 + 2 * 1024 * 1024);
  k_transw<<<dim3(32, 32), dim3(256), 0, stream>>>(Wo, WoT);

  k_gemm<0><<<dim3(64, 24), dim3(256), 0, stream>>>(xb, WT3, 1024, Qf, Kf, Vf, alpha, nullptr);
  k_attn<<<dim3(16, 64), dim3(256), 0, stream>>>(Qf, Kf, Vf, AO);
  k_gemm<1><<<dim3(64, 8), dim3(256), 0, stream>>>(AO, WoT, 1024, nullptr, nullptr, nullptr, nullptr, out);
}

// Round 4
// 303.329 us; speedup vs baseline: 4.2728x; 1.5937x over previous
//
#include <hip/hip_runtime.h>

typedef __bf16 bf16x8 __attribute__((ext_vector_type(8)));
typedef float f32x4 __attribute__((ext_vector_type(4)));
typedef float f32x16 __attribute__((ext_vector_type(16)));

#define MFMA16(a,b,c) __builtin_amdgcn_mfma_f32_16x16x32_bf16(a,b,c,0,0,0)
#define MFMA32(a,b,c) __builtin_amdgcn_mfma_f32_32x32x16_bf16(a,b,c,0,0,0)

__device__ __forceinline__ unsigned short f2bf(float f) {
  unsigned int u = __float_as_uint(f);
  u = (u + 0x7FFFu + ((u >> 16) & 1u)) >> 16;
  return (unsigned short)u;
}

__device__ __forceinline__ void gload16(const void* g, void* l) {
  __builtin_amdgcn_global_load_lds(
      (const __attribute__((address_space(1))) void*)g,
      (__attribute__((address_space(3))) void*)l, 16, 0, 0);
}

// Build PV B-fragment (B[k=key][n=q], k = hi*8 + j) from the 8 fp32 P values
// this lane holds for one 16-key group (C/D order: key = (r&3) + 8*(r>>2) + 4*hi).
// Cross-hi exchange via __shfl_xor(32): deterministic lane i <-> i^32.
__device__ __forceinline__ bf16x8 mk_pfrag(int hi, float p0, float p1, float p2, float p3,
                                           float p4, float p5, float p6, float p7) {
  unsigned int a0, a1, b0, b1;
  asm("v_cvt_pk_bf16_f32 %0, %1, %2" : "=v"(a0) : "v"(p0), "v"(p1));  // keys (0,1)+4hi
  asm("v_cvt_pk_bf16_f32 %0, %1, %2" : "=v"(a1) : "v"(p2), "v"(p3));  // keys (2,3)+4hi
  asm("v_cvt_pk_bf16_f32 %0, %1, %2" : "=v"(b0) : "v"(p4), "v"(p5));  // keys (8,9)+4hi
  asm("v_cvt_pk_bf16_f32 %0, %1, %2" : "=v"(b1) : "v"(p6), "v"(p7));  // keys (10,11)+4hi
  // hi=0 needs partner's a0/a1 (keys 4..7) for words 2,3;
  // hi=1 needs partner's b0/b1 (keys 8..11) for words 0,1.
  unsigned int x = __shfl_xor(hi ? a0 : b0, 32);
  unsigned int y = __shfl_xor(hi ? a1 : b1, 32);
  uint4 w;
  w.x = hi ? x : a0;   // keys hi*8 + (0,1)
  w.y = hi ? y : a1;   // keys hi*8 + (2,3)
  w.z = hi ? b0 : x;   // keys hi*8 + (4,5)
  w.w = hi ? b1 : y;   // keys hi*8 + (6,7)
  return *reinterpret_cast<bf16x8*>(&w);
}

// ---------------- convert x (fp32) -> bf16 ----------------
__global__ __launch_bounds__(256) void k_convx(const float* __restrict__ x,
                                               unsigned short* __restrict__ xb) {
  int i = (blockIdx.x * 256 + threadIdx.x) * 4;
  float4 v = *reinterpret_cast<const float4*>(x + i);
  ushort4 o;
  o.x = f2bf(v.x); o.y = f2bf(v.y); o.z = f2bf(v.z); o.w = f2bf(v.w);
  *reinterpret_cast<ushort4*>(xb + i) = o;
}

// ---------------- transpose-convert W (fp32 [1024][1024]) -> WT bf16 [N][K] ----------------
__global__ __launch_bounds__(256) void k_transw(const float* __restrict__ W,
                                                unsigned short* __restrict__ WT) {
  __shared__ float t[32][33];
  int bx = blockIdx.x * 32;
  int by = blockIdx.y * 32;
  int tx = threadIdx.x & 31;
  int ty = threadIdx.x >> 5;
#pragma unroll
  for (int i = 0; i < 32; i += 8)
    t[ty + i][tx] = W[(size_t)(by + ty + i) * 1024 + bx + tx];
  __syncthreads();
#pragma unroll
  for (int i = 0; i < 32; i += 8)
    WT[(size_t)(bx + ty + i) * 1024 + by + tx] = f2bf(t[tx][ty + i]);
}

// ---------------- GEMM: C[M,N] = A[M,K] (bf16) @ BT[N,K]^T (bf16) ----------------
template <int EPI>
__global__ __launch_bounds__(256) void k_gemm(
    const unsigned short* __restrict__ A, const unsigned short* __restrict__ BT, int K,
    unsigned short* __restrict__ Qf, unsigned short* __restrict__ Kf,
    unsigned short* __restrict__ Vf, const float* __restrict__ alphaPtr,
    float* __restrict__ Out) {
  __shared__ __align__(16) unsigned short smem[128 * 136];
  unsigned short* AsBase = smem;
  unsigned short* BsBase = smem + 128 * 32;
  const int tid = threadIdx.x;
  const int wave = tid >> 6, lane = tid & 63;
  const int l15 = lane & 15, lg = lane >> 4;
  const int wr = wave >> 1, wc = wave & 1;
  const int bm = blockIdx.x, bn = blockIdx.y;

  f32x4 acc[4][4] = {};
  const unsigned short* Ab = A + (size_t)bm * 128 * K;
  const unsigned short* Bb = BT + (size_t)bn * 128 * K;

  const int r0 = tid >> 2, q0 = (tid & 3) * 8;
  const int r1 = r0 + 64;
  char* ldsA = (char*)AsBase + wave * 1024;
  char* ldsB = (char*)BsBase + wave * 1024;

  for (int k0 = 0; k0 < K; k0 += 32) {
    gload16((const void*)(Ab + (size_t)r0 * K + k0 + q0), ldsA);
    gload16((const void*)(Ab + (size_t)r1 * K + k0 + q0), ldsA + 4096);
    gload16((const void*)(Bb + (size_t)r0 * K + k0 + q0), ldsB);
    gload16((const void*)(Bb + (size_t)r1 * K + k0 + q0), ldsB + 4096);
    __syncthreads();
    bf16x8 af[4], bfr[4];
#pragma unroll
    for (int mi = 0; mi < 4; ++mi)
      af[mi] = *reinterpret_cast<const bf16x8*>(&AsBase[(wr * 64 + mi * 16 + l15) * 32 + lg * 8]);
#pragma unroll
    for (int ni = 0; ni < 4; ++ni)
      bfr[ni] = *reinterpret_cast<const bf16x8*>(&BsBase[(wc * 64 + ni * 16 + l15) * 32 + lg * 8]);
#pragma unroll
    for (int mi = 0; mi < 4; ++mi)
#pragma unroll
      for (int ni = 0; ni < 4; ++ni)
        acc[mi][ni] = MFMA16(af[mi], bfr[ni], acc[mi][ni]);
    __syncthreads();
  }

  if (EPI == 0) {
    const float av = alphaPtr[0];
    const int t = bn >> 3;
#pragma unroll
    for (int mi = 0; mi < 4; ++mi)
#pragma unroll
      for (int ni = 0; ni < 4; ++ni)
#pragma unroll
        for (int r = 0; r < 4; ++r) {
          int row = wr * 64 + mi * 16 + lg * 4 + r;
          int col = wc * 64 + ni * 16 + l15;
          float v = acc[mi][ni][r];
          if (t == 0) v += 0.1f * sinf(v);
          else if (t == 1) v += 0.1f * cosf(v);
          else v += av * 0.1f * tanhf(v);
          smem[row * 136 + col] = f2bf(v);
        }
    __syncthreads();
    unsigned short* dst = (t == 0) ? Qf : (t == 1) ? Kf : Vf;
    const int c16 = tid & 15, rb = tid >> 4;
    const int ncol0 = (bn & 7) * 128;
#pragma unroll
    for (int i2 = 0; i2 < 8; ++i2) {
      int srow = rb + i2 * 16;
      uint4 val = *reinterpret_cast<const uint4*>(&smem[srow * 136 + c16 * 8]);
      *reinterpret_cast<uint4*>(dst + (size_t)(bm * 128 + srow) * 1024 + ncol0 + c16 * 8) = val;
    }
  } else {
#pragma unroll
    for (int ni = 0; ni < 4; ++ni) {
      int n = bn * 128 + wc * 64 + ni * 16 + l15;
#pragma unroll
      for (int mi = 0; mi < 4; ++mi) {
        int row = bm * 128 + wr * 64 + mi * 16 + lg * 4;
#pragma unroll
        for (int r = 0; r < 4; ++r)
          Out[(size_t)(row + r) * 1024 + n] = acc[mi][ni][r];
      }
    }
  }
}

// ---------------- flash attention, swapped-operand 32x32 ----------------
// Q,K,V [4][2048][1024] bf16 (col = h*64+d). grid (S/128, B*H), 4 waves x 32 q rows.
__global__ __launch_bounds__(256) void k_attn(const unsigned short* __restrict__ Qf,
                                              const unsigned short* __restrict__ Kf,
                                              const unsigned short* __restrict__ Vf,
                                              unsigned short* __restrict__ AO) {
  __shared__ __align__(16) unsigned short smem[2 * 64 * 72];  // Ks[64][72] | VTs[64][72]
  unsigned short* Ks = smem;
  unsigned short* VTs = smem + 64 * 72;
  const int tid = threadIdx.x;
  const int wave = tid >> 6, lane = tid & 63;
  const int l31 = lane & 31, hi = lane >> 5;
  const int qb = blockIdx.x, bh = blockIdx.y;
  const int b = bh >> 4, h = bh & 15;

  const unsigned short* Qb = Qf + ((size_t)b * 2048 + qb * 128 + wave * 32) * 1024 + h * 64;
  const unsigned short* Kb = Kf + (size_t)b * 2048 * 1024 + h * 64;
  const unsigned short* Vb = Vf + (size_t)b * 2048 * 1024 + h * 64;

  // hoist Q fragments: B[n=q][k=d], lane q=l31, d = ds*16 + hi*8 + j
  bf16x8 qfr[4];
#pragma unroll
  for (int ds = 0; ds < 4; ++ds)
    qfr[ds] = *reinterpret_cast<const bf16x8*>(Qb + (size_t)l31 * 1024 + ds * 16 + hi * 8);

  float mrun = -1.0e30f, lsum = 0.f;
  f32x16 o0 = {}, o1 = {};  // out^T[d][q]: o0 -> d 0..31, o1 -> d 32..63

  const int sr = tid >> 3, sc = (tid & 7) * 8;  // staging: row 0..31, col chunk
  uint4 ka0, ka1, va0, va1;
  ka0 = *reinterpret_cast<const uint4*>(Kb + (size_t)sr * 1024 + sc);
  ka1 = *reinterpret_cast<const uint4*>(Kb + (size_t)(sr + 32) * 1024 + sc);
  va0 = *reinterpret_cast<const uint4*>(Vb + (size_t)sr * 1024 + sc);
  va1 = *reinterpret_cast<const uint4*>(Vb + (size_t)(sr + 32) * 1024 + sc);

  for (int t = 0; t < 32; ++t) {
    // ---- stage regs -> LDS ----
    *reinterpret_cast<uint4*>(&Ks[sr * 72 + sc]) = ka0;
    *reinterpret_cast<uint4*>(&Ks[(sr + 32) * 72 + sc]) = ka1;
    {
      unsigned int w0[4] = {va0.x, va0.y, va0.z, va0.w};
      unsigned int w1[4] = {va1.x, va1.y, va1.z, va1.w};
#pragma unroll
      for (int e = 0; e < 4; ++e) {
        VTs[(sc + 2 * e) * 72 + sr] = (unsigned short)w0[e];
        VTs[(sc + 2 * e + 1) * 72 + sr] = (unsigned short)(w0[e] >> 16);
        VTs[(sc + 2 * e) * 72 + sr + 32] = (unsigned short)w1[e];
        VTs[(sc + 2 * e + 1) * 72 + sr + 32] = (unsigned short)(w1[e] >> 16);
      }
    }
    __syncthreads();

    // ---- prefetch next tile (overlaps compute) ----
    if (t < 31) {
      int kn = (t + 1) * 64;
      ka0 = *reinterpret_cast<const uint4*>(Kb + (size_t)(kn + sr) * 1024 + sc);
      ka1 = *reinterpret_cast<const uint4*>(Kb + (size_t)(kn + sr + 32) * 1024 + sc);
      va0 = *reinterpret_cast<const uint4*>(Vb + (size_t)(kn + sr) * 1024 + sc);
      va1 = *reinterpret_cast<const uint4*>(Vb + (size_t)(kn + sr + 32) * 1024 + sc);
    }

    // ---- QK^T swapped: S^T[key][q] = MFMA(A=K, B=Q) ----
    f32x16 s0 = {}, s1 = {};
#pragma unroll
    for (int ds = 0; ds < 4; ++ds) {
      bf16x8 kf0 = *reinterpret_cast<const bf16x8*>(&Ks[l31 * 72 + ds * 16 + hi * 8]);
      bf16x8 kf1 = *reinterpret_cast<const bf16x8*>(&Ks[(l31 + 32) * 72 + ds * 16 + hi * 8]);
      s0 = MFMA32(kf0, qfr[ds], s0);
      s1 = MFMA32(kf1, qfr[ds], s1);
    }

    // ---- softmax (lane-local row; raw-score domain, scale 0.125 folded in exp) ----
    float pm0 = s0[0], pm1 = s0[1], pm2 = s0[2], pm3 = s0[3];
#pragma unroll
    for (int r = 4; r < 16; r += 4) {
      pm0 = fmaxf(pm0, s0[r]);     pm1 = fmaxf(pm1, s0[r + 1]);
      pm2 = fmaxf(pm2, s0[r + 2]); pm3 = fmaxf(pm3, s0[r + 3]);
    }
#pragma unroll
    for (int r = 0; r < 16; r += 4) {
      pm0 = fmaxf(pm0, s1[r]);     pm1 = fmaxf(pm1, s1[r + 1]);
      pm2 = fmaxf(pm2, s1[r + 2]); pm3 = fmaxf(pm3, s1[r + 3]);
    }
    float pmax = fmaxf(fmaxf(pm0, pm1), fmaxf(pm2, pm3));
    pmax = fmaxf(pmax, __shfl_xor(pmax, 32));

    if (!__all(pmax - mrun <= 64.0f)) {  // 64 raw = 8 scaled (defer-max)
      float mn = fmaxf(mrun, pmax);
      float corr = __expf((mrun - mn) * 0.125f);
      o0 *= corr; o1 *= corr; lsum *= corr;
      mrun = mn;
    }
    const float mm = mrun * 0.125f;
    float rs0 = 0.f, rs1 = 0.f, rs2 = 0.f, rs3 = 0.f;
#pragma unroll
    for (int r = 0; r < 16; r += 4) {
      float p0 = __expf(fmaf(s0[r], 0.125f, -mm));     s0[r] = p0;     rs0 += p0;
      float p1 = __expf(fmaf(s0[r + 1], 0.125f, -mm)); s0[r + 1] = p1; rs1 += p1;
      float p2 = __expf(fmaf(s0[r + 2], 0.125f, -mm)); s0[r + 2] = p2; rs2 += p2;
      float p3 = __expf(fmaf(s0[r + 3], 0.125f, -mm)); s0[r + 3] = p3; rs3 += p3;
    }
#pragma unroll
    for (int r = 0; r < 16; r += 4) {
      float p0 = __expf(fmaf(s1[r], 0.125f, -mm));     s1[r] = p0;     rs0 += p0;
      float p1 = __expf(fmaf(s1[r + 1], 0.125f, -mm)); s1[r + 1] = p1; rs1 += p1;
      float p2 = __expf(fmaf(s1[r + 2], 0.125f, -mm)); s1[r + 2] = p2; rs2 += p2;
      float p3 = __expf(fmaf(s1[r + 3], 0.125f, -mm)); s1[r + 3] = p3; rs3 += p3;
    }
    float rsum = (rs0 + rs1) + (rs2 + rs3);
    rsum += __shfl_xor(rsum, 32);
    lsum += rsum;

    // ---- P fragments (B[n=q][k=key]) ----
    bf16x8 pf[4];
    pf[0] = mk_pfrag(hi, s0[0], s0[1], s0[2], s0[3], s0[4], s0[5], s0[6], s0[7]);
    pf[1] = mk_pfrag(hi, s0[8], s0[9], s0[10], s0[11], s0[12], s0[13], s0[14], s0[15]);
    pf[2] = mk_pfrag(hi, s1[0], s1[1], s1[2], s1[3], s1[4], s1[5], s1[6], s1[7]);
    pf[3] = mk_pfrag(hi, s1[8], s1[9], s1[10], s1[11], s1[12], s1[13], s1[14], s1[15]);

    // ---- PV swapped: out^T[d][q] += MFMA(A=V^T, B=P) ----
#pragma unroll
    for (int ks = 0; ks < 4; ++ks) {
      bf16x8 v0 = *reinterpret_cast<const bf16x8*>(&VTs[l31 * 72 + ks * 16 + hi * 8]);
      bf16x8 v1 = *reinterpret_cast<const bf16x8*>(&VTs[(l31 + 32) * 72 + ks * 16 + hi * 8]);
      o0 = MFMA32(v0, pf[ks], o0);
      o1 = MFMA32(v1, pf[ks], o1);
    }
    __syncthreads();
  }

  // ---- epilogue: normalize, transpose via LDS, vectorized store ----
  const float inv = 1.0f / lsum;
  unsigned short* OL = smem + wave * 2304;  // [32 q][72]
#pragma unroll
  for (int r = 0; r < 16; ++r) {
    int d0 = (r & 3) + 8 * (r >> 2) + 4 * hi;
    OL[l31 * 72 + d0] = f2bf(o0[r] * inv);
    OL[l31 * 72 + 32 + d0] = f2bf(o1[r] * inv);
  }
  __syncthreads();
#pragma unroll
  for (int p = 0; p < 4; ++p) {
    int u = tid + p * 256;
    int row = u >> 3, ch = u & 7;
    uint4 val = *reinterpret_cast<const uint4*>(&smem[(row >> 5) * 2304 + (row & 31) * 72 + ch * 8]);
    *reinterpret_cast<uint4*>(AO + ((size_t)b * 2048 + qb * 128 + row) * 1024 + h * 64 + ch * 8) = val;
  }
}

extern "C" void kernel_launch(void* const* d_in, const int* in_sizes, int n_in,
                              void* d_out, int out_size, void* d_ws, size_t ws_size,
                              hipStream_t stream) {
  const float* x = (const float*)d_in[0];
  const float* Wq = (const float*)d_in[1];
  const float* Wk = (const float*)d_in[2];
  const float* Wv = (const float*)d_in[3];
  const float* Wo = (const float*)d_in[4];
  const float* alpha = (const float*)d_in[5];
  float* out = (float*)d_out;

  char* ws = (char*)d_ws;
  unsigned short* xb  = (unsigned short*)(ws);
  unsigned short* WT3 = (unsigned short*)(ws + 16777216);
  unsigned short* WoT = (unsigned short*)(ws + 23068672);
  unsigned short* Qf  = (unsigned short*)(ws + 25165824);
  unsigned short* Kf  = (unsigned short*)(ws + 41943040);
  unsigned short* Vf  = (unsigned short*)(ws + 58720256);
  unsigned short* AO  = (unsigned short*)(ws + 75497472);

  k_convx<<<dim3(8192), dim3(256), 0, stream>>>(x, xb);
  k_transw<<<dim3(32, 32), dim3(256), 0, stream>>>(Wq, WT3);
  k_transw<<<dim3(32, 32), dim3(256), 0, stream>>>(Wk, WT3 + 1024 * 1024);
  k_transw<<<dim3(32, 32), dim3(256), 0, stream>>>(Wv, WT3 + 2 * 1024 * 1024);
  k_transw<<<dim3(32, 32), dim3(256), 0, stream>>>(Wo, WoT);

  k_gemm<0><<<dim3(64, 24), dim3(256), 0, stream>>>(xb, WT3, 1024, Qf, Kf, Vf, alpha, nullptr);
  k_attn<<<dim3(16, 64), dim3(256), 0, stream>>>(Qf, Kf, Vf, AO);
  k_gemm<1><<<dim3(64, 8), dim3(256), 0, stream>>>(AO, WoT, 1024, nullptr, nullptr, nullptr, nullptr, out);
}

// Round 5
// 277.297 us; speedup vs baseline: 4.6739x; 1.0939x over previous
//
#include <hip/hip_runtime.h>

typedef __bf16 bf16x8 __attribute__((ext_vector_type(8)));
typedef float f32x4 __attribute__((ext_vector_type(4)));
typedef float f32x16 __attribute__((ext_vector_type(16)));

#define MFMA16(a,b,c) __builtin_amdgcn_mfma_f32_16x16x32_bf16(a,b,c,0,0,0)
#define MFMA32(a,b,c) __builtin_amdgcn_mfma_f32_32x32x16_bf16(a,b,c,0,0,0)

__device__ __forceinline__ unsigned short f2bf(float f) {
  unsigned int u = __float_as_uint(f);
  u = (u + 0x7FFFu + ((u >> 16) & 1u)) >> 16;
  return (unsigned short)u;
}

__device__ __forceinline__ void gload16(const void* g, void* l) {
  __builtin_amdgcn_global_load_lds(
      (const __attribute__((address_space(1))) void*)g,
      (__attribute__((address_space(3))) void*)l, 16, 0, 0);
}

// Build PV B-fragment (B[k=key][n=q], k = hi*8 + j) from the 8 fp32 P values
// this lane holds for one 16-key group (C/D order: key = (r&3) + 8*(r>>2) + 4*hi).
__device__ __forceinline__ bf16x8 mk_pfrag(int hi, float p0, float p1, float p2, float p3,
                                           float p4, float p5, float p6, float p7) {
  unsigned int a0, a1, b0, b1;
  asm("v_cvt_pk_bf16_f32 %0, %1, %2" : "=v"(a0) : "v"(p0), "v"(p1));  // keys (0,1)+4hi
  asm("v_cvt_pk_bf16_f32 %0, %1, %2" : "=v"(a1) : "v"(p2), "v"(p3));  // keys (2,3)+4hi
  asm("v_cvt_pk_bf16_f32 %0, %1, %2" : "=v"(b0) : "v"(p4), "v"(p5));  // keys (8,9)+4hi
  asm("v_cvt_pk_bf16_f32 %0, %1, %2" : "=v"(b1) : "v"(p6), "v"(p7));  // keys (10,11)+4hi
  unsigned int x = __shfl_xor(hi ? a0 : b0, 32);
  unsigned int y = __shfl_xor(hi ? a1 : b1, 32);
  uint4 w;
  w.x = hi ? x : a0;
  w.y = hi ? y : a1;
  w.z = hi ? b0 : x;
  w.w = hi ? b1 : y;
  return *reinterpret_cast<bf16x8*>(&w);
}

// ---------------- convert x (fp32) -> bf16 ----------------
__global__ __launch_bounds__(256) void k_convx(const float* __restrict__ x,
                                               unsigned short* __restrict__ xb) {
  int i = (blockIdx.x * 256 + threadIdx.x) * 4;
  float4 v = *reinterpret_cast<const float4*>(x + i);
  ushort4 o;
  o.x = f2bf(v.x); o.y = f2bf(v.y); o.z = f2bf(v.z); o.w = f2bf(v.w);
  *reinterpret_cast<ushort4*>(xb + i) = o;
}

// ---------------- transpose-convert W (fp32 [1024][1024]) -> WT bf16 [N][K] ----------------
__global__ __launch_bounds__(256) void k_transw(const float* __restrict__ W,
                                                unsigned short* __restrict__ WT) {
  __shared__ float t[32][33];
  int bx = blockIdx.x * 32;
  int by = blockIdx.y * 32;
  int tx = threadIdx.x & 31;
  int ty = threadIdx.x >> 5;
#pragma unroll
  for (int i = 0; i < 32; i += 8)
    t[ty + i][tx] = W[(size_t)(by + ty + i) * 1024 + bx + tx];
  __syncthreads();
#pragma unroll
  for (int i = 0; i < 32; i += 8)
    WT[(size_t)(bx + ty + i) * 1024 + by + tx] = f2bf(t[tx][ty + i]);
}

// ---------------- GEMM: C[M,N] = A[M,K] (bf16) @ BT[N,K]^T (bf16) ----------------
template <int EPI>
__global__ __launch_bounds__(256) void k_gemm(
    const unsigned short* __restrict__ A, const unsigned short* __restrict__ BT, int K,
    unsigned short* __restrict__ Qf, unsigned short* __restrict__ Kf,
    unsigned short* __restrict__ Vf, const float* __restrict__ alphaPtr,
    float* __restrict__ Out) {
  __shared__ __align__(16) unsigned short smem[128 * 136];
  unsigned short* AsBase = smem;
  unsigned short* BsBase = smem + 128 * 32;
  const int tid = threadIdx.x;
  const int wave = tid >> 6, lane = tid & 63;
  const int l15 = lane & 15, lg = lane >> 4;
  const int wr = wave >> 1, wc = wave & 1;
  const int bm = blockIdx.x, bn = blockIdx.y;

  f32x4 acc[4][4] = {};
  const unsigned short* Ab = A + (size_t)bm * 128 * K;
  const unsigned short* Bb = BT + (size_t)bn * 128 * K;

  const int r0 = tid >> 2, q0 = (tid & 3) * 8;
  const int r1 = r0 + 64;
  char* ldsA = (char*)AsBase + wave * 1024;
  char* ldsB = (char*)BsBase + wave * 1024;

  for (int k0 = 0; k0 < K; k0 += 32) {
    gload16((const void*)(Ab + (size_t)r0 * K + k0 + q0), ldsA);
    gload16((const void*)(Ab + (size_t)r1 * K + k0 + q0), ldsA + 4096);
    gload16((const void*)(Bb + (size_t)r0 * K + k0 + q0), ldsB);
    gload16((const void*)(Bb + (size_t)r1 * K + k0 + q0), ldsB + 4096);
    __syncthreads();
    bf16x8 af[4], bfr[4];
#pragma unroll
    for (int mi = 0; mi < 4; ++mi)
      af[mi] = *reinterpret_cast<const bf16x8*>(&AsBase[(wr * 64 + mi * 16 + l15) * 32 + lg * 8]);
#pragma unroll
    for (int ni = 0; ni < 4; ++ni)
      bfr[ni] = *reinterpret_cast<const bf16x8*>(&BsBase[(wc * 64 + ni * 16 + l15) * 32 + lg * 8]);
#pragma unroll
    for (int mi = 0; mi < 4; ++mi)
#pragma unroll
      for (int ni = 0; ni < 4; ++ni)
        acc[mi][ni] = MFMA16(af[mi], bfr[ni], acc[mi][ni]);
    __syncthreads();
  }

  if (EPI == 0) {
    const float av = alphaPtr[0];
    const int t = bn >> 3;
#pragma unroll
    for (int mi = 0; mi < 4; ++mi)
#pragma unroll
      for (int ni = 0; ni < 4; ++ni)
#pragma unroll
        for (int r = 0; r < 4; ++r) {
          int row = wr * 64 + mi * 16 + lg * 4 + r;
          int col = wc * 64 + ni * 16 + l15;
          float v = acc[mi][ni][r];
          if (t == 0) v += 0.1f * sinf(v);
          else if (t == 1) v += 0.1f * cosf(v);
          else v += av * 0.1f * tanhf(v);
          smem[row * 136 + col] = f2bf(v);
        }
    __syncthreads();
    unsigned short* dst = (t == 0) ? Qf : (t == 1) ? Kf : Vf;
    const int c16 = tid & 15, rb = tid >> 4;
    const int ncol0 = (bn & 7) * 128;
#pragma unroll
    for (int i2 = 0; i2 < 8; ++i2) {
      int srow = rb + i2 * 16;
      uint4 val = *reinterpret_cast<const uint4*>(&smem[srow * 136 + c16 * 8]);
      *reinterpret_cast<uint4*>(dst + (size_t)(bm * 128 + srow) * 1024 + ncol0 + c16 * 8) = val;
    }
  } else {
#pragma unroll
    for (int ni = 0; ni < 4; ++ni) {
      int n = bn * 128 + wc * 64 + ni * 16 + l15;
#pragma unroll
      for (int mi = 0; mi < 4; ++mi) {
        int row = bm * 128 + wr * 64 + mi * 16 + lg * 4;
#pragma unroll
        for (int r = 0; r < 4; ++r)
          Out[(size_t)(row + r) * 1024 + n] = acc[mi][ni][r];
      }
    }
  }
}

// ---------------- flash attention, swapped-operand 32x32, double-buffered ----------------
// Q,K,V [4][2048][1024] bf16 (col = h*64+d). grid (S/128, B*H), 4 waves x 32 q rows.
// VT swizzle: elem idx ^= ((d>>3)&7)<<3 (16B-granular; write/read identical).
__global__ __launch_bounds__(256) void k_attn(const unsigned short* __restrict__ Qf,
                                              const unsigned short* __restrict__ Kf,
                                              const unsigned short* __restrict__ Vf,
                                              unsigned short* __restrict__ AO) {
  __shared__ __align__(16) unsigned short smem[4 * 64 * 72];  // Ks0|VT0|Ks1|VT1
  const int BUF = 64 * 72;
  const int tid = threadIdx.x;
  const int wave = tid >> 6, lane = tid & 63;
  const int l31 = lane & 31, hi = lane >> 5;
  const int qb = blockIdx.x, bh = blockIdx.y;
  const int b = bh >> 4, h = bh & 15;

  const unsigned short* Qb = Qf + ((size_t)b * 2048 + qb * 128 + wave * 32) * 1024 + h * 64;
  const unsigned short* Kb = Kf + (size_t)b * 2048 * 1024 + h * 64;
  const unsigned short* Vb = Vf + (size_t)b * 2048 * 1024 + h * 64;

  // hoist Q fragments: B[n=q][k=d], lane q=l31, d = ds*16 + hi*8 + j
  bf16x8 qfr[4];
#pragma unroll
  for (int ds = 0; ds < 4; ++ds)
    qfr[ds] = *reinterpret_cast<const bf16x8*>(Qb + (size_t)l31 * 1024 + ds * 16 + hi * 8);

  float mrun = -1.0e30f, lsum = 0.f;
  f32x16 o0 = {}, o1 = {};  // out^T[d][q]: o0 -> d 0..31, o1 -> d 32..63

  const int sr = tid >> 3, sc = (tid & 7) * 8;  // staging: row, col chunk
  const int u8 = tid & 7;                        // = sc>>3 = V swizzle key
  const int swz0 = (l31 >> 3) << 3;              // read swizzle, d = l31
  const int swz1 = ((l31 >> 3) ^ 4) << 3;        // read swizzle, d = l31+32

  uint4 ka0, ka1, va0, va1;
  ka0 = *reinterpret_cast<const uint4*>(Kb + (size_t)sr * 1024 + sc);
  ka1 = *reinterpret_cast<const uint4*>(Kb + (size_t)(sr + 32) * 1024 + sc);
  va0 = *reinterpret_cast<const uint4*>(Vb + (size_t)sr * 1024 + sc);
  va1 = *reinterpret_cast<const uint4*>(Vb + (size_t)(sr + 32) * 1024 + sc);

  // ---- prologue: stage tile 0 into buffer 0 ----
  {
    unsigned short* Ks = smem;
    unsigned short* VT = smem + BUF;
    *reinterpret_cast<uint4*>(&Ks[sr * 72 + sc]) = ka0;
    *reinterpret_cast<uint4*>(&Ks[(sr + 32) * 72 + sc]) = ka1;
    unsigned int w0[4] = {va0.x, va0.y, va0.z, va0.w};
    unsigned int w1[4] = {va1.x, va1.y, va1.z, va1.w};
#pragma unroll
    for (int e = 0; e < 4; ++e) {
      int d = sc + 2 * e;
      VT[(d * 72 + sr) ^ (u8 << 3)] = (unsigned short)w0[e];
      VT[((d + 1) * 72 + sr) ^ (u8 << 3)] = (unsigned short)(w0[e] >> 16);
      VT[(d * 72 + sr + 32) ^ (u8 << 3)] = (unsigned short)w1[e];
      VT[((d + 1) * 72 + sr + 32) ^ (u8 << 3)] = (unsigned short)(w1[e] >> 16);
    }
  }
  __syncthreads();

  for (int t = 0; t < 32; ++t) {
    unsigned short* KsC = smem + (t & 1) * 2 * BUF;
    unsigned short* VTC = KsC + BUF;
    unsigned short* KsN = smem + ((t + 1) & 1) * 2 * BUF;
    unsigned short* VTN = KsN + BUF;

    // ---- issue next-tile global loads early ----
    if (t < 31) {
      int kn = (t + 1) * 64;
      ka0 = *reinterpret_cast<const uint4*>(Kb + (size_t)(kn + sr) * 1024 + sc);
      ka1 = *reinterpret_cast<const uint4*>(Kb + (size_t)(kn + sr + 32) * 1024 + sc);
      va0 = *reinterpret_cast<const uint4*>(Vb + (size_t)(kn + sr) * 1024 + sc);
      va1 = *reinterpret_cast<const uint4*>(Vb + (size_t)(kn + sr + 32) * 1024 + sc);
    }

    // ---- QK^T swapped: S^T[key][q] = MFMA(A=K, B=Q) ----
    f32x16 s0 = {}, s1 = {};
    __builtin_amdgcn_s_setprio(1);
#pragma unroll
    for (int ds = 0; ds < 4; ++ds) {
      bf16x8 kf0 = *reinterpret_cast<const bf16x8*>(&KsC[l31 * 72 + ds * 16 + hi * 8]);
      bf16x8 kf1 = *reinterpret_cast<const bf16x8*>(&KsC[(l31 + 32) * 72 + ds * 16 + hi * 8]);
      s0 = MFMA32(kf0, qfr[ds], s0);
      s1 = MFMA32(kf1, qfr[ds], s1);
    }
    __builtin_amdgcn_s_setprio(0);

    // ---- softmax (lane-local row; scale 0.125 folded in exp) ----
    float pm0 = s0[0], pm1 = s0[1], pm2 = s0[2], pm3 = s0[3];
#pragma unroll
    for (int r = 4; r < 16; r += 4) {
      pm0 = fmaxf(pm0, s0[r]);     pm1 = fmaxf(pm1, s0[r + 1]);
      pm2 = fmaxf(pm2, s0[r + 2]); pm3 = fmaxf(pm3, s0[r + 3]);
    }
#pragma unroll
    for (int r = 0; r < 16; r += 4) {
      pm0 = fmaxf(pm0, s1[r]);     pm1 = fmaxf(pm1, s1[r + 1]);
      pm2 = fmaxf(pm2, s1[r + 2]); pm3 = fmaxf(pm3, s1[r + 3]);
    }
    float pmax = fmaxf(fmaxf(pm0, pm1), fmaxf(pm2, pm3));
    pmax = fmaxf(pmax, __shfl_xor(pmax, 32));

    if (!__all(pmax - mrun <= 64.0f)) {  // 64 raw = 8 scaled (defer-max)
      float mn = fmaxf(mrun, pmax);
      float corr = __expf((mrun - mn) * 0.125f);
      o0 *= corr; o1 *= corr; lsum *= corr;
      mrun = mn;
    }
    const float mm = mrun * 0.125f;
    float rs0 = 0.f, rs1 = 0.f, rs2 = 0.f, rs3 = 0.f;
#pragma unroll
    for (int r = 0; r < 16; r += 4) {
      float p0 = __expf(fmaf(s0[r], 0.125f, -mm));     s0[r] = p0;     rs0 += p0;
      float p1 = __expf(fmaf(s0[r + 1], 0.125f, -mm)); s0[r + 1] = p1; rs1 += p1;
      float p2 = __expf(fmaf(s0[r + 2], 0.125f, -mm)); s0[r + 2] = p2; rs2 += p2;
      float p3 = __expf(fmaf(s0[r + 3], 0.125f, -mm)); s0[r + 3] = p3; rs3 += p3;
    }
#pragma unroll
    for (int r = 0; r < 16; r += 4) {
      float p0 = __expf(fmaf(s1[r], 0.125f, -mm));     s1[r] = p0;     rs0 += p0;
      float p1 = __expf(fmaf(s1[r + 1], 0.125f, -mm)); s1[r + 1] = p1; rs1 += p1;
      float p2 = __expf(fmaf(s1[r + 2], 0.125f, -mm)); s1[r + 2] = p2; rs2 += p2;
      float p3 = __expf(fmaf(s1[r + 3], 0.125f, -mm)); s1[r + 3] = p3; rs3 += p3;
    }
    float rsum = (rs0 + rs1) + (rs2 + rs3);
    rsum += __shfl_xor(rsum, 32);
    lsum += rsum;

    // ---- stage next tile regs -> LDS (overlaps with PV below via scheduler) ----
    if (t < 31) {
      *reinterpret_cast<uint4*>(&KsN[sr * 72 + sc]) = ka0;
      *reinterpret_cast<uint4*>(&KsN[(sr + 32) * 72 + sc]) = ka1;
      unsigned int w0[4] = {va0.x, va0.y, va0.z, va0.w};
      unsigned int w1[4] = {va1.x, va1.y, va1.z, va1.w};
#pragma unroll
      for (int e = 0; e < 4; ++e) {
        int d = sc + 2 * e;
        VTN[(d * 72 + sr) ^ (u8 << 3)] = (unsigned short)w0[e];
        VTN[((d + 1) * 72 + sr) ^ (u8 << 3)] = (unsigned short)(w0[e] >> 16);
        VTN[(d * 72 + sr + 32) ^ (u8 << 3)] = (unsigned short)w1[e];
        VTN[((d + 1) * 72 + sr + 32) ^ (u8 << 3)] = (unsigned short)(w1[e] >> 16);
      }
    }

    // ---- P fragments (B[k=key][n=q]) ----
    bf16x8 pf[4];
    pf[0] = mk_pfrag(hi, s0[0], s0[1], s0[2], s0[3], s0[4], s0[5], s0[6], s0[7]);
    pf[1] = mk_pfrag(hi, s0[8], s0[9], s0[10], s0[11], s0[12], s0[13], s0[14], s0[15]);
    pf[2] = mk_pfrag(hi, s1[0], s1[1], s1[2], s1[3], s1[4], s1[5], s1[6], s1[7]);
    pf[3] = mk_pfrag(hi, s1[8], s1[9], s1[10], s1[11], s1[12], s1[13], s1[14], s1[15]);

    // ---- PV swapped: out^T[d][q] += MFMA(A=V^T, B=P) ----
    __builtin_amdgcn_s_setprio(1);
#pragma unroll
    for (int ks = 0; ks < 4; ++ks) {
      bf16x8 v0 = *reinterpret_cast<const bf16x8*>(&VTC[(l31 * 72 + ks * 16 + hi * 8) ^ swz0]);
      bf16x8 v1 = *reinterpret_cast<const bf16x8*>(&VTC[((l31 + 32) * 72 + ks * 16 + hi * 8) ^ swz1]);
      o0 = MFMA32(v0, pf[ks], o0);
      o1 = MFMA32(v1, pf[ks], o1);
    }
    __builtin_amdgcn_s_setprio(0);
    __syncthreads();
  }

  // ---- epilogue: normalize, transpose via LDS, vectorized store ----
  const float inv = 1.0f / lsum;
  unsigned short* OL = smem + wave * 2304;  // [32 q][72]
#pragma unroll
  for (int r = 0; r < 16; ++r) {
    int d0 = (r & 3) + 8 * (r >> 2) + 4 * hi;
    OL[l31 * 72 + d0] = f2bf(o0[r] * inv);
    OL[l31 * 72 + 32 + d0] = f2bf(o1[r] * inv);
  }
  __syncthreads();
#pragma unroll
  for (int p = 0; p < 4; ++p) {
    int u = tid + p * 256;
    int row = u >> 3, ch = u & 7;
    uint4 val = *reinterpret_cast<const uint4*>(&smem[(row >> 5) * 2304 + (row & 31) * 72 + ch * 8]);
    *reinterpret_cast<uint4*>(AO + ((size_t)b * 2048 + qb * 128 + row) * 1024 + h * 64 + ch * 8) = val;
  }
}

extern "C" void kernel_launch(void* const* d_in, const int* in_sizes, int n_in,
                              void* d_out, int out_size, void* d_ws, size_t ws_size,
                              hipStream_t stream) {
  const float* x = (const float*)d_in[0];
  const float* Wq = (const float*)d_in[1];
  const float* Wk = (const float*)d_in[2];
  const float* Wv = (const float*)d_in[3];
  const float* Wo = (const float*)d_in[4];
  const float* alpha = (const float*)d_in[5];
  float* out = (float*)d_out;

  char* ws = (char*)d_ws;
  unsigned short* xb  = (unsigned short*)(ws);
  unsigned short* WT3 = (unsigned short*)(ws + 16777216);
  unsigned short* WoT = (unsigned short*)(ws + 23068672);
  unsigned short* Qf  = (unsigned short*)(ws + 25165824);
  unsigned short* Kf  = (unsigned short*)(ws + 41943040);
  unsigned short* Vf  = (unsigned short*)(ws + 58720256);
  unsigned short* AO  = (unsigned short*)(ws + 75497472);

  k_convx<<<dim3(8192), dim3(256), 0, stream>>>(x, xb);
  k_transw<<<dim3(32, 32), dim3(256), 0, stream>>>(Wq, WT3);
  k_transw<<<dim3(32, 32), dim3(256), 0, stream>>>(Wk, WT3 + 1024 * 1024);
  k_transw<<<dim3(32, 32), dim3(256), 0, stream>>>(Wv, WT3 + 2 * 1024 * 1024);
  k_transw<<<dim3(32, 32), dim3(256), 0, stream>>>(Wo, WoT);

  k_gemm<0><<<dim3(64, 24), dim3(256), 0, stream>>>(xb, WT3, 1024, Qf, Kf, Vf, alpha, nullptr);
  k_attn<<<dim3(16, 64), dim3(256), 0, stream>>>(Qf, Kf, Vf, AO);
  k_gemm<1><<<dim3(64, 8), dim3(256), 0, stream>>>(AO, WoT, 1024, nullptr, nullptr, nullptr, nullptr, out);
}

// Round 6
// 276.150 us; speedup vs baseline: 4.6934x; 1.0042x over previous
//
#include <hip/hip_runtime.h>

typedef __bf16 bf16x8 __attribute__((ext_vector_type(8)));
typedef float f32x4 __attribute__((ext_vector_type(4)));
typedef float f32x16 __attribute__((ext_vector_type(16)));

#define MFMA16(a,b,c) __builtin_amdgcn_mfma_f32_16x16x32_bf16(a,b,c,0,0,0)
#define MFMA32(a,b,c) __builtin_amdgcn_mfma_f32_32x32x16_bf16(a,b,c,0,0,0)

__device__ __forceinline__ unsigned short f2bf(float f) {
  unsigned int u = __float_as_uint(f);
  u = (u + 0x7FFFu + ((u >> 16) & 1u)) >> 16;
  return (unsigned short)u;
}

__device__ __forceinline__ void gload16(const void* g, void* l) {
  __builtin_amdgcn_global_load_lds(
      (const __attribute__((address_space(1))) void*)g,
      (__attribute__((address_space(3))) void*)l, 16, 0, 0);
}

__device__ __forceinline__ float vexp2(float x) {
  float r;
  asm("v_exp_f32 %0, %1" : "=v"(r) : "v"(x));
  return r;
}

// Build PV B-fragment (B[k=key][n=q], k = hi*8 + j) from the 8 fp32 P values
// this lane holds for one 16-key group (C/D order: key = (r&3) + 8*(r>>2) + 4*hi).
__device__ __forceinline__ bf16x8 mk_pfrag(int hi, float p0, float p1, float p2, float p3,
                                           float p4, float p5, float p6, float p7) {
  unsigned int a0, a1, b0, b1;
  asm("v_cvt_pk_bf16_f32 %0, %1, %2" : "=v"(a0) : "v"(p0), "v"(p1));  // keys (0,1)+4hi
  asm("v_cvt_pk_bf16_f32 %0, %1, %2" : "=v"(a1) : "v"(p2), "v"(p3));  // keys (2,3)+4hi
  asm("v_cvt_pk_bf16_f32 %0, %1, %2" : "=v"(b0) : "v"(p4), "v"(p5));  // keys (8,9)+4hi
  asm("v_cvt_pk_bf16_f32 %0, %1, %2" : "=v"(b1) : "v"(p6), "v"(p7));  // keys (10,11)+4hi
  unsigned int x = __shfl_xor(hi ? a0 : b0, 32);
  unsigned int y = __shfl_xor(hi ? a1 : b1, 32);
  uint4 w;
  w.x = hi ? x : a0;
  w.y = hi ? y : a1;
  w.z = hi ? b0 : x;
  w.w = hi ? b1 : y;
  return *reinterpret_cast<bf16x8*>(&w);
}

// ---------------- convert x (fp32) -> bf16 ----------------
__global__ __launch_bounds__(256) void k_convx(const float* __restrict__ x,
                                               unsigned short* __restrict__ xb) {
  int i = (blockIdx.x * 256 + threadIdx.x) * 4;
  float4 v = *reinterpret_cast<const float4*>(x + i);
  ushort4 o;
  o.x = f2bf(v.x); o.y = f2bf(v.y); o.z = f2bf(v.z); o.w = f2bf(v.w);
  *reinterpret_cast<ushort4*>(xb + i) = o;
}

// ---------------- transpose-convert W (fp32 [1024][1024]) -> WT bf16 [N][K] ----------------
__global__ __launch_bounds__(256) void k_transw(const float* __restrict__ W,
                                                unsigned short* __restrict__ WT) {
  __shared__ float t[32][33];
  int bx = blockIdx.x * 32;
  int by = blockIdx.y * 32;
  int tx = threadIdx.x & 31;
  int ty = threadIdx.x >> 5;
#pragma unroll
  for (int i = 0; i < 32; i += 8)
    t[ty + i][tx] = W[(size_t)(by + ty + i) * 1024 + bx + tx];
  __syncthreads();
#pragma unroll
  for (int i = 0; i < 32; i += 8)
    WT[(size_t)(bx + ty + i) * 1024 + by + tx] = f2bf(t[tx][ty + i]);
}

// ---------------- GEMM: C[M,N] = A[M,K] (bf16) @ BT[N,K]^T (bf16) ----------------
template <int EPI>
__global__ __launch_bounds__(256) void k_gemm(
    const unsigned short* __restrict__ A, const unsigned short* __restrict__ BT, int K,
    unsigned short* __restrict__ Qf, unsigned short* __restrict__ Kf,
    unsigned short* __restrict__ Vf, const float* __restrict__ alphaPtr,
    float* __restrict__ Out) {
  __shared__ __align__(16) unsigned short smem[128 * 136];
  unsigned short* AsBase = smem;
  unsigned short* BsBase = smem + 128 * 32;
  const int tid = threadIdx.x;
  const int wave = tid >> 6, lane = tid & 63;
  const int l15 = lane & 15, lg = lane >> 4;
  const int wr = wave >> 1, wc = wave & 1;
  const int bm = blockIdx.x, bn = blockIdx.y;

  f32x4 acc[4][4] = {};
  const unsigned short* Ab = A + (size_t)bm * 128 * K;
  const unsigned short* Bb = BT + (size_t)bn * 128 * K;

  const int r0 = tid >> 2, q0 = (tid & 3) * 8;
  const int r1 = r0 + 64;
  char* ldsA = (char*)AsBase + wave * 1024;
  char* ldsB = (char*)BsBase + wave * 1024;

  for (int k0 = 0; k0 < K; k0 += 32) {
    gload16((const void*)(Ab + (size_t)r0 * K + k0 + q0), ldsA);
    gload16((const void*)(Ab + (size_t)r1 * K + k0 + q0), ldsA + 4096);
    gload16((const void*)(Bb + (size_t)r0 * K + k0 + q0), ldsB);
    gload16((const void*)(Bb + (size_t)r1 * K + k0 + q0), ldsB + 4096);
    __syncthreads();
    bf16x8 af[4], bfr[4];
#pragma unroll
    for (int mi = 0; mi < 4; ++mi)
      af[mi] = *reinterpret_cast<const bf16x8*>(&AsBase[(wr * 64 + mi * 16 + l15) * 32 + lg * 8]);
#pragma unroll
    for (int ni = 0; ni < 4; ++ni)
      bfr[ni] = *reinterpret_cast<const bf16x8*>(&BsBase[(wc * 64 + ni * 16 + l15) * 32 + lg * 8]);
#pragma unroll
    for (int mi = 0; mi < 4; ++mi)
#pragma unroll
      for (int ni = 0; ni < 4; ++ni)
        acc[mi][ni] = MFMA16(af[mi], bfr[ni], acc[mi][ni]);
    __syncthreads();
  }

  if (EPI == 0) {
    const float av = alphaPtr[0];
    const int t = bn >> 3;
#pragma unroll
    for (int mi = 0; mi < 4; ++mi)
#pragma unroll
      for (int ni = 0; ni < 4; ++ni)
#pragma unroll
        for (int r = 0; r < 4; ++r) {
          int row = wr * 64 + mi * 16 + lg * 4 + r;
          int col = wc * 64 + ni * 16 + l15;
          float v = acc[mi][ni][r];
          if (t == 0) v += 0.1f * sinf(v);
          else if (t == 1) v += 0.1f * cosf(v);
          else v += av * 0.1f * tanhf(v);
          smem[row * 136 + col] = f2bf(v);
        }
    __syncthreads();
    unsigned short* dst = (t == 0) ? Qf : (t == 1) ? Kf : Vf;
    const int c16 = tid & 15, rb = tid >> 4;
    const int ncol0 = (bn & 7) * 128;
#pragma unroll
    for (int i2 = 0; i2 < 8; ++i2) {
      int srow = rb + i2 * 16;
      uint4 val = *reinterpret_cast<const uint4*>(&smem[srow * 136 + c16 * 8]);
      *reinterpret_cast<uint4*>(dst + (size_t)(bm * 128 + srow) * 1024 + ncol0 + c16 * 8) = val;
    }
  } else {
#pragma unroll
    for (int ni = 0; ni < 4; ++ni) {
      int n = bn * 128 + wc * 64 + ni * 16 + l15;
#pragma unroll
      for (int mi = 0; mi < 4; ++mi) {
        int row = bm * 128 + wr * 64 + mi * 16 + lg * 4;
#pragma unroll
        for (int r = 0; r < 4; ++r)
          Out[(size_t)(row + r) * 1024 + n] = acc[mi][ni][r];
      }
    }
  }
}

// ---------------- flash attention, swapped-operand 32x32, double-buffered ----------------
// Q,K,V [4][2048][1024] bf16 (col = h*64+d). grid (S/128, B*H), 4 waves x 32 q rows.
// K: global_load_lds into unpadded [64][64]; 16B-chunk swizzle c_stored = c ^ (row&7),
//    realized by inverse-swizzling the per-lane GLOBAL source (rule: linear dest).
// VT: reg-staged transpose into [d][key] pad-72 with elem-XOR swizzle (as R5).
__global__ __launch_bounds__(256, 4) void k_attn(const unsigned short* __restrict__ Qf,
                                                 const unsigned short* __restrict__ Kf,
                                                 const unsigned short* __restrict__ Vf,
                                                 unsigned short* __restrict__ AO) {
  __shared__ __align__(16) unsigned short smem[2 * (4096 + 4608)];  // [Ks0|VT0|Ks1|VT1]
  const int tid = threadIdx.x;
  const int wave = tid >> 6, lane = tid & 63;
  const int l31 = lane & 31, hi = lane >> 5;
  const int qb = blockIdx.x, bh = blockIdx.y;
  const int b = bh >> 4, h = bh & 15;

  const unsigned short* Qb = Qf + ((size_t)b * 2048 + qb * 128 + wave * 32) * 1024 + h * 64;
  const unsigned short* Kb = Kf + (size_t)b * 2048 * 1024 + h * 64;
  const unsigned short* Vb = Vf + (size_t)b * 2048 * 1024 + h * 64;

  // hoist Q fragments: B[n=q][k=d], lane q=l31, d = ds*16 + hi*8 + j
  bf16x8 qfr[4];
#pragma unroll
  for (int ds = 0; ds < 4; ++ds)
    qfr[ds] = *reinterpret_cast<const bf16x8*>(Qb + (size_t)l31 * 1024 + ds * 16 + hi * 8);

  float mrun = -1.0e30f, lsum = 0.f;
  f32x16 o0 = {}, o1 = {};  // out^T[d][q]: o0 -> d 0..31, o1 -> d 32..63

  // K gload source mapping (per-lane, loop-invariant):
  // call j covers rows wave*16 + j*8 + (lane>>3); stored chunk (lane&7) holds
  // global chunk (lane&7)^(lane>>3)  [since row&7 == lane>>3].
  const int krow0 = wave * 16 + (lane >> 3);         // + j*8
  const int ksrcc = ((lane & 7) ^ (lane >> 3)) << 3; // elem offset in row
  const int kxor = l31 & 7;                          // read-side chunk XOR

  // V staging (reg -> transposed LDS)
  const int sr = tid >> 3, sc = (tid & 7) * 8;
  const int u8 = tid & 7;
  const int swz0 = (l31 >> 3) << 3;
  const int swz1 = ((l31 >> 3) ^ 4) << 3;

  const float C1 = 0.18033688011112042f;  // 0.125 * log2(e)

  uint4 va0, va1;
  va0 = *reinterpret_cast<const uint4*>(Vb + (size_t)sr * 1024 + sc);
  va1 = *reinterpret_cast<const uint4*>(Vb + (size_t)(sr + 32) * 1024 + sc);

  // ---- prologue: stage tile 0 into buffer 0 ----
  {
    unsigned short* Ks = smem;
    unsigned short* VT = smem + 4096;
    gload16((const void*)(Kb + (size_t)krow0 * 1024 + ksrcc), (char*)Ks + wave * 2048);
    gload16((const void*)(Kb + (size_t)(krow0 + 8) * 1024 + ksrcc), (char*)Ks + wave * 2048 + 1024);
    unsigned int w0[4] = {va0.x, va0.y, va0.z, va0.w};
    unsigned int w1[4] = {va1.x, va1.y, va1.z, va1.w};
#pragma unroll
    for (int e = 0; e < 4; ++e) {
      int d = sc + 2 * e;
      VT[(d * 72 + sr) ^ (u8 << 3)] = (unsigned short)w0[e];
      VT[((d + 1) * 72 + sr) ^ (u8 << 3)] = (unsigned short)(w0[e] >> 16);
      VT[(d * 72 + sr + 32) ^ (u8 << 3)] = (unsigned short)w1[e];
      VT[((d + 1) * 72 + sr + 32) ^ (u8 << 3)] = (unsigned short)(w1[e] >> 16);
    }
  }
  __syncthreads();

  for (int t = 0; t < 32; ++t) {
    unsigned short* KsC = smem + (t & 1) * 8704;
    unsigned short* VTC = KsC + 4096;
    unsigned short* KsN = smem + ((t + 1) & 1) * 8704;
    unsigned short* VTN = KsN + 4096;

    // ---- issue next-tile loads early (K direct-to-LDS; V to regs) ----
    if (t < 31) {
      int kn = (t + 1) * 64;
      gload16((const void*)(Kb + (size_t)(kn + krow0) * 1024 + ksrcc), (char*)KsN + wave * 2048);
      gload16((const void*)(Kb + (size_t)(kn + krow0 + 8) * 1024 + ksrcc),
              (char*)KsN + wave * 2048 + 1024);
      va0 = *reinterpret_cast<const uint4*>(Vb + (size_t)(kn + sr) * 1024 + sc);
      va1 = *reinterpret_cast<const uint4*>(Vb + (size_t)(kn + sr + 32) * 1024 + sc);
    }

    // ---- QK^T swapped: S^T[key][q] = MFMA(A=K, B=Q) ----
    f32x16 s0 = {}, s1 = {};
    __builtin_amdgcn_s_setprio(1);
#pragma unroll
    for (int ds = 0; ds < 4; ++ds) {
      int ch = ((ds * 2 + hi) ^ kxor) * 8;
      bf16x8 kf0 = *reinterpret_cast<const bf16x8*>(&KsC[l31 * 64 + ch]);
      bf16x8 kf1 = *reinterpret_cast<const bf16x8*>(&KsC[(l31 + 32) * 64 + ch]);
      s0 = MFMA32(kf0, qfr[ds], s0);
      s1 = MFMA32(kf1, qfr[ds], s1);
    }
    __builtin_amdgcn_s_setprio(0);

    // ---- softmax (lane-local row; p = 2^(s*C1 + c2)) ----
    float pm0 = s0[0], pm1 = s0[1], pm2 = s0[2], pm3 = s0[3];
#pragma unroll
    for (int r = 4; r < 16; r += 4) {
      pm0 = fmaxf(pm0, s0[r]);     pm1 = fmaxf(pm1, s0[r + 1]);
      pm2 = fmaxf(pm2, s0[r + 2]); pm3 = fmaxf(pm3, s0[r + 3]);
    }
#pragma unroll
    for (int r = 0; r < 16; r += 4) {
      pm0 = fmaxf(pm0, s1[r]);     pm1 = fmaxf(pm1, s1[r + 1]);
      pm2 = fmaxf(pm2, s1[r + 2]); pm3 = fmaxf(pm3, s1[r + 3]);
    }
    float pmax = fmaxf(fmaxf(pm0, pm1), fmaxf(pm2, pm3));
    pmax = fmaxf(pmax, __shfl_xor(pmax, 32));

    if (!__all(pmax - mrun <= 64.0f)) {  // 64 raw = 8 scaled (defer-max)
      float mn = fmaxf(mrun, pmax);
      float corr = vexp2((mrun - mn) * C1);
      o0 *= corr; o1 *= corr; lsum *= corr;
      mrun = mn;
    }
    const float c2 = -mrun * C1;
    float rs0 = 0.f, rs1 = 0.f, rs2 = 0.f, rs3 = 0.f;
#pragma unroll
    for (int r = 0; r < 16; r += 4) {
      float p0 = vexp2(fmaf(s0[r], C1, c2));     s0[r] = p0;     rs0 += p0;
      float p1 = vexp2(fmaf(s0[r + 1], C1, c2)); s0[r + 1] = p1; rs1 += p1;
      float p2 = vexp2(fmaf(s0[r + 2], C1, c2)); s0[r + 2] = p2; rs2 += p2;
      float p3 = vexp2(fmaf(s0[r + 3], C1, c2)); s0[r + 3] = p3; rs3 += p3;
    }
#pragma unroll
    for (int r = 0; r < 16; r += 4) {
      float p0 = vexp2(fmaf(s1[r], C1, c2));     s1[r] = p0;     rs0 += p0;
      float p1 = vexp2(fmaf(s1[r + 1], C1, c2)); s1[r + 1] = p1; rs1 += p1;
      float p2 = vexp2(fmaf(s1[r + 2], C1, c2)); s1[r + 2] = p2; rs2 += p2;
      float p3 = vexp2(fmaf(s1[r + 3], C1, c2)); s1[r + 3] = p3; rs3 += p3;
    }
    float rsum = (rs0 + rs1) + (rs2 + rs3);
    rsum += __shfl_xor(rsum, 32);
    lsum += rsum;

    // ---- stage next V tile regs -> LDS ----
    if (t < 31) {
      unsigned int w0[4] = {va0.x, va0.y, va0.z, va0.w};
      unsigned int w1[4] = {va1.x, va1.y, va1.z, va1.w};
#pragma unroll
      for (int e = 0; e < 4; ++e) {
        int d = sc + 2 * e;
        VTN[(d * 72 + sr) ^ (u8 << 3)] = (unsigned short)w0[e];
        VTN[((d + 1) * 72 + sr) ^ (u8 << 3)] = (unsigned short)(w0[e] >> 16);
        VTN[(d * 72 + sr + 32) ^ (u8 << 3)] = (unsigned short)w1[e];
        VTN[((d + 1) * 72 + sr + 32) ^ (u8 << 3)] = (unsigned short)(w1[e] >> 16);
      }
    }

    // ---- PV swapped: out^T[d][q] += MFMA(A=V^T, B=P); pf built per-ks ----
    __builtin_amdgcn_s_setprio(1);
#pragma unroll
    for (int ks = 0; ks < 4; ++ks) {
      bf16x8 pf =
          (ks == 0) ? mk_pfrag(hi, s0[0], s0[1], s0[2], s0[3], s0[4], s0[5], s0[6], s0[7])
        : (ks == 1) ? mk_pfrag(hi, s0[8], s0[9], s0[10], s0[11], s0[12], s0[13], s0[14], s0[15])
        : (ks == 2) ? mk_pfrag(hi, s1[0], s1[1], s1[2], s1[3], s1[4], s1[5], s1[6], s1[7])
                    : mk_pfrag(hi, s1[8], s1[9], s1[10], s1[11], s1[12], s1[13], s1[14], s1[15]);
      bf16x8 v0 = *reinterpret_cast<const bf16x8*>(&VTC[(l31 * 72 + ks * 16 + hi * 8) ^ swz0]);
      bf16x8 v1 = *reinterpret_cast<const bf16x8*>(&VTC[((l31 + 32) * 72 + ks * 16 + hi * 8) ^ swz1]);
      o0 = MFMA32(v0, pf, o0);
      o1 = MFMA32(v1, pf, o1);
    }
    __builtin_amdgcn_s_setprio(0);
    __syncthreads();
  }

  // ---- epilogue: normalize, transpose via LDS, vectorized store ----
  const float inv = 1.0f / lsum;
  unsigned short* OL = smem + wave * 2304;  // [32 q][72]
#pragma unroll
  for (int r = 0; r < 16; ++r) {
    int d0 = (r & 3) + 8 * (r >> 2) + 4 * hi;
    OL[l31 * 72 + d0] = f2bf(o0[r] * inv);
    OL[l31 * 72 + 32 + d0] = f2bf(o1[r] * inv);
  }
  __syncthreads();
#pragma unroll
  for (int p = 0; p < 4; ++p) {
    int u = tid + p * 256;
    int row = u >> 3, ch = u & 7;
    uint4 val = *reinterpret_cast<const uint4*>(&smem[(row >> 5) * 2304 + (row & 31) * 72 + ch * 8]);
    *reinterpret_cast<uint4*>(AO + ((size_t)b * 2048 + qb * 128 + row) * 1024 + h * 64 + ch * 8) = val;
  }
}

extern "C" void kernel_launch(void* const* d_in, const int* in_sizes, int n_in,
                              void* d_out, int out_size, void* d_ws, size_t ws_size,
                              hipStream_t stream) {
  const float* x = (const float*)d_in[0];
  const float* Wq = (const float*)d_in[1];
  const float* Wk = (const float*)d_in[2];
  const float* Wv = (const float*)d_in[3];
  const float* Wo = (const float*)d_in[4];
  const float* alpha = (const float*)d_in[5];
  float* out = (float*)d_out;

  char* ws = (char*)d_ws;
  unsigned short* xb  = (unsigned short*)(ws);
  unsigned short* WT3 = (unsigned short*)(ws + 16777216);
  unsigned short* WoT = (unsigned short*)(ws + 23068672);
  unsigned short* Qf  = (unsigned short*)(ws + 25165824);
  unsigned short* Kf  = (unsigned short*)(ws + 41943040);
  unsigned short* Vf  = (unsigned short*)(ws + 58720256);
  unsigned short* AO  = (unsigned short*)(ws + 75497472);

  k_convx<<<dim3(8192), dim3(256), 0, stream>>>(x, xb);
  k_transw<<<dim3(32, 32), dim3(256), 0, stream>>>(Wq, WT3);
  k_transw<<<dim3(32, 32), dim3(256), 0, stream>>>(Wk, WT3 + 1024 * 1024);
  k_transw<<<dim3(32, 32), dim3(256), 0, stream>>>(Wv, WT3 + 2 * 1024 * 1024);
  k_transw<<<dim3(32, 32), dim3(256), 0, stream>>>(Wo, WoT);

  k_gemm<0><<<dim3(64, 24), dim3(256), 0, stream>>>(xb, WT3, 1024, Qf, Kf, Vf, alpha, nullptr);
  k_attn<<<dim3(16, 64), dim3(256), 0, stream>>>(Qf, Kf, Vf, AO);
  k_gemm<1><<<dim3(64, 8), dim3(256), 0, stream>>>(AO, WoT, 1024, nullptr, nullptr, nullptr, nullptr, out);
}

// Round 7
// 234.729 us; speedup vs baseline: 5.5215x; 1.1765x over previous
//
#include <hip/hip_runtime.h>

typedef __bf16 bf16x8 __attribute__((ext_vector_type(8)));
typedef float f32x4 __attribute__((ext_vector_type(4)));
typedef float f32x16 __attribute__((ext_vector_type(16)));

#define MFMA16(a,b,c) __builtin_amdgcn_mfma_f32_16x16x32_bf16(a,b,c,0,0,0)
#define MFMA32(a,b,c) __builtin_amdgcn_mfma_f32_32x32x16_bf16(a,b,c,0,0,0)

__device__ __forceinline__ unsigned short f2bf(float f) {
  unsigned int u = __float_as_uint(f);
  u = (u + 0x7FFFu + ((u >> 16) & 1u)) >> 16;
  return (unsigned short)u;
}

__device__ __forceinline__ void gload16(const void* g, void* l) {
  __builtin_amdgcn_global_load_lds(
      (const __attribute__((address_space(1))) void*)g,
      (__attribute__((address_space(3))) void*)l, 16, 0, 0);
}

__device__ __forceinline__ float vexp2(float x) {
  float r;
  asm("v_exp_f32 %0, %1" : "=v"(r) : "v"(x));
  return r;
}

// Build PV B-fragment (B[k=key][n=q], k = hi*8 + j) from the 8 fp32 P values
// this lane holds for one 16-key group (C/D order: key = (r&3) + 8*(r>>2) + 4*hi).
__device__ __forceinline__ bf16x8 mk_pfrag(int hi, float p0, float p1, float p2, float p3,
                                           float p4, float p5, float p6, float p7) {
  unsigned int a0, a1, b0, b1;
  asm("v_cvt_pk_bf16_f32 %0, %1, %2" : "=v"(a0) : "v"(p0), "v"(p1));  // keys (0,1)+4hi
  asm("v_cvt_pk_bf16_f32 %0, %1, %2" : "=v"(a1) : "v"(p2), "v"(p3));  // keys (2,3)+4hi
  asm("v_cvt_pk_bf16_f32 %0, %1, %2" : "=v"(b0) : "v"(p4), "v"(p5));  // keys (8,9)+4hi
  asm("v_cvt_pk_bf16_f32 %0, %1, %2" : "=v"(b1) : "v"(p6), "v"(p7));  // keys (10,11)+4hi
  unsigned int x = __shfl_xor(hi ? a0 : b0, 32);
  unsigned int y = __shfl_xor(hi ? a1 : b1, 32);
  uint4 w;
  w.x = hi ? x : a0;
  w.y = hi ? y : a1;
  w.z = hi ? b0 : x;
  w.w = hi ? b1 : y;
  return *reinterpret_cast<bf16x8*>(&w);
}

// ---------------- convert x (fp32) -> bf16 ----------------
__global__ __launch_bounds__(256) void k_convx(const float* __restrict__ x,
                                               unsigned short* __restrict__ xb) {
  int i = (blockIdx.x * 256 + threadIdx.x) * 4;
  float4 v = *reinterpret_cast<const float4*>(x + i);
  ushort4 o;
  o.x = f2bf(v.x); o.y = f2bf(v.y); o.z = f2bf(v.z); o.w = f2bf(v.w);
  *reinterpret_cast<ushort4*>(xb + i) = o;
}

// ---------------- transpose-convert W (fp32 [1024][1024]) -> WT bf16 [N][K] ----------------
__global__ __launch_bounds__(256) void k_transw(const float* __restrict__ W,
                                                unsigned short* __restrict__ WT) {
  __shared__ float t[32][33];
  int bx = blockIdx.x * 32;
  int by = blockIdx.y * 32;
  int tx = threadIdx.x & 31;
  int ty = threadIdx.x >> 5;
#pragma unroll
  for (int i = 0; i < 32; i += 8)
    t[ty + i][tx] = W[(size_t)(by + ty + i) * 1024 + bx + tx];
  __syncthreads();
#pragma unroll
  for (int i = 0; i < 32; i += 8)
    WT[(size_t)(bx + ty + i) * 1024 + by + tx] = f2bf(t[tx][ty + i]);
}

// ---------------- GEMM: C[M,N] = A[M,K] (bf16) @ BT[N,K]^T (bf16) ----------------
template <int EPI>
__global__ __launch_bounds__(256) void k_gemm(
    const unsigned short* __restrict__ A, const unsigned short* __restrict__ BT, int K,
    unsigned short* __restrict__ Qf, unsigned short* __restrict__ Kf,
    unsigned short* __restrict__ Vf, const float* __restrict__ alphaPtr,
    float* __restrict__ Out) {
  __shared__ __align__(16) unsigned short smem[128 * 136];
  unsigned short* AsBase = smem;
  unsigned short* BsBase = smem + 128 * 32;
  const int tid = threadIdx.x;
  const int wave = tid >> 6, lane = tid & 63;
  const int l15 = lane & 15, lg = lane >> 4;
  const int wr = wave >> 1, wc = wave & 1;
  const int bm = blockIdx.x, bn = blockIdx.y;

  f32x4 acc[4][4] = {};
  const unsigned short* Ab = A + (size_t)bm * 128 * K;
  const unsigned short* Bb = BT + (size_t)bn * 128 * K;

  const int r0 = tid >> 2, q0 = (tid & 3) * 8;
  const int r1 = r0 + 64;
  char* ldsA = (char*)AsBase + wave * 1024;
  char* ldsB = (char*)BsBase + wave * 1024;

  for (int k0 = 0; k0 < K; k0 += 32) {
    gload16((const void*)(Ab + (size_t)r0 * K + k0 + q0), ldsA);
    gload16((const void*)(Ab + (size_t)r1 * K + k0 + q0), ldsA + 4096);
    gload16((const void*)(Bb + (size_t)r0 * K + k0 + q0), ldsB);
    gload16((const void*)(Bb + (size_t)r1 * K + k0 + q0), ldsB + 4096);
    __syncthreads();
    bf16x8 af[4], bfr[4];
#pragma unroll
    for (int mi = 0; mi < 4; ++mi)
      af[mi] = *reinterpret_cast<const bf16x8*>(&AsBase[(wr * 64 + mi * 16 + l15) * 32 + lg * 8]);
#pragma unroll
    for (int ni = 0; ni < 4; ++ni)
      bfr[ni] = *reinterpret_cast<const bf16x8*>(&BsBase[(wc * 64 + ni * 16 + l15) * 32 + lg * 8]);
#pragma unroll
    for (int mi = 0; mi < 4; ++mi)
#pragma unroll
      for (int ni = 0; ni < 4; ++ni)
        acc[mi][ni] = MFMA16(af[mi], bfr[ni], acc[mi][ni]);
    __syncthreads();
  }

  if (EPI == 0) {
    const float av = alphaPtr[0];
    const int t = bn >> 3;
#pragma unroll
    for (int mi = 0; mi < 4; ++mi)
#pragma unroll
      for (int ni = 0; ni < 4; ++ni)
#pragma unroll
        for (int r = 0; r < 4; ++r) {
          int row = wr * 64 + mi * 16 + lg * 4 + r;
          int col = wc * 64 + ni * 16 + l15;
          float v = acc[mi][ni][r];
          // fast native transforms (error ~1e-6 << bf16 threshold margin)
          if (t == 0) v += 0.1f * __sinf(v);
          else if (t == 1) v += 0.1f * __cosf(v);
          else {
            float e = __expf(2.0f * v);
            v += av * 0.1f * (1.0f - 2.0f * __builtin_amdgcn_rcpf(e + 1.0f));
          }
          smem[row * 136 + col] = f2bf(v);
        }
    __syncthreads();
    unsigned short* dst = (t == 0) ? Qf : (t == 1) ? Kf : Vf;
    const int c16 = tid & 15, rb = tid >> 4;
    const int ncol0 = (bn & 7) * 128;
#pragma unroll
    for (int i2 = 0; i2 < 8; ++i2) {
      int srow = rb + i2 * 16;
      uint4 val = *reinterpret_cast<const uint4*>(&smem[srow * 136 + c16 * 8]);
      *reinterpret_cast<uint4*>(dst + (size_t)(bm * 128 + srow) * 1024 + ncol0 + c16 * 8) = val;
    }
  } else {
#pragma unroll
    for (int ni = 0; ni < 4; ++ni) {
      int n = bn * 128 + wc * 64 + ni * 16 + l15;
#pragma unroll
      for (int mi = 0; mi < 4; ++mi) {
        int row = bm * 128 + wr * 64 + mi * 16 + lg * 4;
#pragma unroll
        for (int r = 0; r < 4; ++r)
          Out[(size_t)(row + r) * 1024 + n] = acc[mi][ni][r];
      }
    }
  }
}

// ---------------- flash attention, swapped-operand 32x32, double-buffered ----------------
// Q,K,V [4][2048][1024] bf16 (col = h*64+d). grid (S/128, B*H), 4 waves x 32 q rows.
// XCD-chunked block remap: all 16 qb-sharers of one (b,h) K/V panel land on one XCD.
__global__ __launch_bounds__(256, 4) void k_attn(const unsigned short* __restrict__ Qf,
                                                 const unsigned short* __restrict__ Kf,
                                                 const unsigned short* __restrict__ Vf,
                                                 unsigned short* __restrict__ AO) {
  __shared__ __align__(16) unsigned short smem[2 * (4096 + 4608)];  // [Ks0|VT0|Ks1|VT1]
  const int tid = threadIdx.x;
  const int wave = tid >> 6, lane = tid & 63;
  const int l31 = lane & 31, hi = lane >> 5;
  // physical linear id (x fastest) -> XCD-chunked work id (1024 blocks, 8 XCDs, 128 each)
  const int f = (blockIdx.y << 4) | blockIdx.x;
  const int nf = ((f & 7) << 7) | (f >> 3);
  const int qb = nf & 15, bh = nf >> 4;
  const int b = bh >> 4, h = bh & 15;

  const unsigned short* Qb = Qf + ((size_t)b * 2048 + qb * 128 + wave * 32) * 1024 + h * 64;
  const unsigned short* Kb = Kf + (size_t)b * 2048 * 1024 + h * 64;
  const unsigned short* Vb = Vf + (size_t)b * 2048 * 1024 + h * 64;

  // hoist Q fragments: B[n=q][k=d], lane q=l31, d = ds*16 + hi*8 + j
  bf16x8 qfr[4];
#pragma unroll
  for (int ds = 0; ds < 4; ++ds)
    qfr[ds] = *reinterpret_cast<const bf16x8*>(Qb + (size_t)l31 * 1024 + ds * 16 + hi * 8);

  float mrun = -1.0e30f, lsum = 0.f;
  f32x16 o0 = {}, o1 = {};  // out^T[d][q]: o0 -> d 0..31, o1 -> d 32..63

  // K gload source mapping (per-lane, loop-invariant)
  const int krow0 = wave * 16 + (lane >> 3);         // + j*8
  const int ksrcc = ((lane & 7) ^ (lane >> 3)) << 3; // elem offset in row
  const int kxor = l31 & 7;                          // read-side chunk XOR

  // V staging (reg -> transposed LDS)
  const int sr = tid >> 3, sc = (tid & 7) * 8;
  const int u8 = tid & 7;
  const int swz0 = (l31 >> 3) << 3;
  const int swz1 = ((l31 >> 3) ^ 4) << 3;

  const float C1 = 0.18033688011112042f;  // 0.125 * log2(e)

  uint4 va0, va1;
  va0 = *reinterpret_cast<const uint4*>(Vb + (size_t)sr * 1024 + sc);
  va1 = *reinterpret_cast<const uint4*>(Vb + (size_t)(sr + 32) * 1024 + sc);

  // ---- prologue: stage tile 0 into buffer 0 ----
  {
    unsigned short* Ks = smem;
    unsigned short* VT = smem + 4096;
    gload16((const void*)(Kb + (size_t)krow0 * 1024 + ksrcc), (char*)Ks + wave * 2048);
    gload16((const void*)(Kb + (size_t)(krow0 + 8) * 1024 + ksrcc), (char*)Ks + wave * 2048 + 1024);
    unsigned int w0[4] = {va0.x, va0.y, va0.z, va0.w};
    unsigned int w1[4] = {va1.x, va1.y, va1.z, va1.w};
#pragma unroll
    for (int e = 0; e < 4; ++e) {
      int d = sc + 2 * e;
      VT[(d * 72 + sr) ^ (u8 << 3)] = (unsigned short)w0[e];
      VT[((d + 1) * 72 + sr) ^ (u8 << 3)] = (unsigned short)(w0[e] >> 16);
      VT[(d * 72 + sr + 32) ^ (u8 << 3)] = (unsigned short)w1[e];
      VT[((d + 1) * 72 + sr + 32) ^ (u8 << 3)] = (unsigned short)(w1[e] >> 16);
    }
  }
  __syncthreads();

  for (int t = 0; t < 32; ++t) {
    unsigned short* KsC = smem + (t & 1) * 8704;
    unsigned short* VTC = KsC + 4096;
    unsigned short* KsN = smem + ((t + 1) & 1) * 8704;
    unsigned short* VTN = KsN + 4096;

    // ---- issue next-tile loads early (K direct-to-LDS; V to regs) ----
    if (t < 31) {
      int kn = (t + 1) * 64;
      gload16((const void*)(Kb + (size_t)(kn + krow0) * 1024 + ksrcc), (char*)KsN + wave * 2048);
      gload16((const void*)(Kb + (size_t)(kn + krow0 + 8) * 1024 + ksrcc),
              (char*)KsN + wave * 2048 + 1024);
      va0 = *reinterpret_cast<const uint4*>(Vb + (size_t)(kn + sr) * 1024 + sc);
      va1 = *reinterpret_cast<const uint4*>(Vb + (size_t)(kn + sr + 32) * 1024 + sc);
    }

    // ---- QK^T swapped: S^T[key][q] = MFMA(A=K, B=Q) ----
    f32x16 s0 = {}, s1 = {};
    __builtin_amdgcn_s_setprio(1);
#pragma unroll
    for (int ds = 0; ds < 4; ++ds) {
      int ch = ((ds * 2 + hi) ^ kxor) * 8;
      bf16x8 kf0 = *reinterpret_cast<const bf16x8*>(&KsC[l31 * 64 + ch]);
      bf16x8 kf1 = *reinterpret_cast<const bf16x8*>(&KsC[(l31 + 32) * 64 + ch]);
      s0 = MFMA32(kf0, qfr[ds], s0);
      s1 = MFMA32(kf1, qfr[ds], s1);
    }
    __builtin_amdgcn_s_setprio(0);

    // ---- softmax (lane-local row; p = 2^(s*C1 + c2)) ----
    float pm0 = s0[0], pm1 = s0[1], pm2 = s0[2], pm3 = s0[3];
#pragma unroll
    for (int r = 4; r < 16; r += 4) {
      pm0 = fmaxf(pm0, s0[r]);     pm1 = fmaxf(pm1, s0[r + 1]);
      pm2 = fmaxf(pm2, s0[r + 2]); pm3 = fmaxf(pm3, s0[r + 3]);
    }
#pragma unroll
    for (int r = 0; r < 16; r += 4) {
      pm0 = fmaxf(pm0, s1[r]);     pm1 = fmaxf(pm1, s1[r + 1]);
      pm2 = fmaxf(pm2, s1[r + 2]); pm3 = fmaxf(pm3, s1[r + 3]);
    }
    float pmax = fmaxf(fmaxf(pm0, pm1), fmaxf(pm2, pm3));
    pmax = fmaxf(pmax, __shfl_xor(pmax, 32));

    if (!__all(pmax - mrun <= 64.0f)) {  // 64 raw = 8 scaled (defer-max)
      float mn = fmaxf(mrun, pmax);
      float corr = vexp2((mrun - mn) * C1);
      o0 *= corr; o1 *= corr; lsum *= corr;
      mrun = mn;
    }
    const float c2 = -mrun * C1;
    float rs0 = 0.f, rs1 = 0.f, rs2 = 0.f, rs3 = 0.f;
#pragma unroll
    for (int r = 0; r < 16; r += 4) {
      float p0 = vexp2(fmaf(s0[r], C1, c2));     s0[r] = p0;     rs0 += p0;
      float p1 = vexp2(fmaf(s0[r + 1], C1, c2)); s0[r + 1] = p1; rs1 += p1;
      float p2 = vexp2(fmaf(s0[r + 2], C1, c2)); s0[r + 2] = p2; rs2 += p2;
      float p3 = vexp2(fmaf(s0[r + 3], C1, c2)); s0[r + 3] = p3; rs3 += p3;
    }
#pragma unroll
    for (int r = 0; r < 16; r += 4) {
      float p0 = vexp2(fmaf(s1[r], C1, c2));     s1[r] = p0;     rs0 += p0;
      float p1 = vexp2(fmaf(s1[r + 1], C1, c2)); s1[r + 1] = p1; rs1 += p1;
      float p2 = vexp2(fmaf(s1[r + 2], C1, c2)); s1[r + 2] = p2; rs2 += p2;
      float p3 = vexp2(fmaf(s1[r + 3], C1, c2)); s1[r + 3] = p3; rs3 += p3;
    }
    float rsum = (rs0 + rs1) + (rs2 + rs3);
    rsum += __shfl_xor(rsum, 32);
    lsum += rsum;

    // ---- stage next V tile regs -> LDS ----
    if (t < 31) {
      unsigned int w0[4] = {va0.x, va0.y, va0.z, va0.w};
      unsigned int w1[4] = {va1.x, va1.y, va1.z, va1.w};
#pragma unroll
      for (int e = 0; e < 4; ++e) {
        int d = sc + 2 * e;
        VTN[(d * 72 + sr) ^ (u8 << 3)] = (unsigned short)w0[e];
        VTN[((d + 1) * 72 + sr) ^ (u8 << 3)] = (unsigned short)(w0[e] >> 16);
        VTN[(d * 72 + sr + 32) ^ (u8 << 3)] = (unsigned short)w1[e];
        VTN[((d + 1) * 72 + sr + 32) ^ (u8 << 3)] = (unsigned short)(w1[e] >> 16);
      }
    }

    // ---- PV swapped: out^T[d][q] += MFMA(A=V^T, B=P); pf built per-ks ----
    __builtin_amdgcn_s_setprio(1);
#pragma unroll
    for (int ks = 0; ks < 4; ++ks) {
      bf16x8 pf =
          (ks == 0) ? mk_pfrag(hi, s0[0], s0[1], s0[2], s0[3], s0[4], s0[5], s0[6], s0[7])
        : (ks == 1) ? mk_pfrag(hi, s0[8], s0[9], s0[10], s0[11], s0[12], s0[13], s0[14], s0[15])
        : (ks == 2) ? mk_pfrag(hi, s1[0], s1[1], s1[2], s1[3], s1[4], s1[5], s1[6], s1[7])
                    : mk_pfrag(hi, s1[8], s1[9], s1[10], s1[11], s1[12], s1[13], s1[14], s1[15]);
      bf16x8 v0 = *reinterpret_cast<const bf16x8*>(&VTC[(l31 * 72 + ks * 16 + hi * 8) ^ swz0]);
      bf16x8 v1 = *reinterpret_cast<const bf16x8*>(&VTC[((l31 + 32) * 72 + ks * 16 + hi * 8) ^ swz1]);
      o0 = MFMA32(v0, pf, o0);
      o1 = MFMA32(v1, pf, o1);
    }
    __builtin_amdgcn_s_setprio(0);
    __syncthreads();
  }

  // ---- epilogue: normalize, transpose via LDS, vectorized store ----
  const float inv = 1.0f / lsum;
  unsigned short* OL = smem + wave * 2304;  // [32 q][72]
#pragma unroll
  for (int r = 0; r < 16; ++r) {
    int d0 = (r & 3) + 8 * (r >> 2) + 4 * hi;
    OL[l31 * 72 + d0] = f2bf(o0[r] * inv);
    OL[l31 * 72 + 32 + d0] = f2bf(o1[r] * inv);
  }
  __syncthreads();
#pragma unroll
  for (int p = 0; p < 4; ++p) {
    int u = tid + p * 256;
    int row = u >> 3, ch = u & 7;
    uint4 val = *reinterpret_cast<const uint4*>(&smem[(row >> 5) * 2304 + (row & 31) * 72 + ch * 8]);
    *reinterpret_cast<uint4*>(AO + ((size_t)b * 2048 + qb * 128 + row) * 1024 + h * 64 + ch * 8) = val;
  }
}

extern "C" void kernel_launch(void* const* d_in, const int* in_sizes, int n_in,
                              void* d_out, int out_size, void* d_ws, size_t ws_size,
                              hipStream_t stream) {
  const float* x = (const float*)d_in[0];
  const float* Wq = (const float*)d_in[1];
  const float* Wk = (const float*)d_in[2];
  const float* Wv = (const float*)d_in[3];
  const float* Wo = (const float*)d_in[4];
  const float* alpha = (const float*)d_in[5];
  float* out = (float*)d_out;

  char* ws = (char*)d_ws;
  unsigned short* xb  = (unsigned short*)(ws);
  unsigned short* WT3 = (unsigned short*)(ws + 16777216);
  unsigned short* WoT = (unsigned short*)(ws + 23068672);
  unsigned short* Qf  = (unsigned short*)(ws + 25165824);
  unsigned short* Kf  = (unsigned short*)(ws + 41943040);
  unsigned short* Vf  = (unsigned short*)(ws + 58720256);
  unsigned short* AO  = (unsigned short*)(ws + 75497472);

  k_convx<<<dim3(8192), dim3(256), 0, stream>>>(x, xb);
  k_transw<<<dim3(32, 32), dim3(256), 0, stream>>>(Wq, WT3);
  k_transw<<<dim3(32, 32), dim3(256), 0, stream>>>(Wk, WT3 + 1024 * 1024);
  k_transw<<<dim3(32, 32), dim3(256), 0, stream>>>(Wv, WT3 + 2 * 1024 * 1024);
  k_transw<<<dim3(32, 32), dim3(256), 0, stream>>>(Wo, WoT);

  k_gemm<0><<<dim3(64, 24), dim3(256), 0, stream>>>(xb, WT3, 1024, Qf, Kf, Vf, alpha, nullptr);
  k_attn<<<dim3(16, 64), dim3(256), 0, stream>>>(Qf, Kf, Vf, AO);
  k_gemm<1><<<dim3(64, 8), dim3(256), 0, stream>>>(AO, WoT, 1024, nullptr, nullptr, nullptr, nullptr, out);
}